// Round 12
// baseline (2015.824 us; speedup 1.0000x reference)
//
#include <hip/hip_runtime.h>
#include <stdint.h>

// ---------------------------------------------------------------------------
// DGCNN forward on MI355X. All fp32. B=8 graphs x N=2048 nodes, D0=6, K=10.
// BN folded into following layer weights; max-pools on raw activations via
// monotone-affine trick; x5 branch of m0 reduced to [8,1024]@[1024,256].
// R11: knn64 retiled to 2 rows x 16 cols/thread (16 rows x 1024 j per block,
// 2048 blocks) — keeps 2-row B-sharing (LDS floor ~95us) at acc=32 VGPR for
// 5 waves/SIMD; row_sq fused into knn staging (sq accumulated from staged B);
// zero+wprep fused into one prep kernel. 35 -> 29 dispatches.
// ---------------------------------------------------------------------------

constexpr int T  = 16384;   // total nodes
constexpr int NBG = 8;      // graphs
constexpr int NN = 2048;    // nodes per graph
constexpr int KK = 10;      // kNN
constexpr float BN_EPS = 1e-5f;

__device__ __forceinline__ unsigned fkey(float f) {
  unsigned u = __float_as_uint(f);
  return (u & 0x80000000u) ? ~u : (u | 0x80000000u);
}
__device__ __forceinline__ float funkey(unsigned k) {
  unsigned u = (k & 0x80000000u) ? (k ^ 0x80000000u) : ~k;
  return __uint_as_float(u);
}

__device__ __forceinline__ void ins10(unsigned long long (&b)[KK],
                                      unsigned long long v) {
  b[KK - 1] = v;
#pragma unroll
  for (int s = KK - 1; s > 0; --s)
    if (b[s] < b[s - 1]) {
      unsigned long long t2 = b[s]; b[s] = b[s - 1]; b[s - 1] = t2;
    }
}

// ---------------------------------------------------------------- prep
// blocks 0..71: zero stats/cmax/cmin; 72..75: wprep conv1 (D=6);
// 76..108: wprep conv2; 109..141: wprep conv3.
__global__ void prep_kernel(float* __restrict__ stats,
                            unsigned* __restrict__ cmax, unsigned* __restrict__ cmin,
                            const float* __restrict__ w0a, const float* __restrict__ b0a,
                            const float* __restrict__ w0b, const float* __restrict__ b0b,
                            const float* __restrict__ w0c, const float* __restrict__ b0c,
                            float* __restrict__ wpa, float* __restrict__ bpa,
                            float* __restrict__ wpb, float* __restrict__ bpb,
                            float* __restrict__ wpc, float* __restrict__ bpc) {
  const int blk = blockIdx.x, tid = threadIdx.x;
  if (blk < 72) {
    const int gid = blk * 256 + tid;
    if (gid < 9 * 2048) stats[gid] = 0.f;
    if (gid < NBG * 1024) { cmax[gid] = 0u; cmin[gid] = 0xFFFFFFFFu; }
    return;
  }
  const float* w0; const float* b0; float* wp; float* bp; int D, gid;
  if (blk < 76)       { w0 = w0a; b0 = b0a; wp = wpa; bp = bpa; D = 6;  gid = (blk - 72) * 256 + tid; }
  else if (blk < 109) { w0 = w0b; b0 = b0b; wp = wpb; bp = bpb; D = 64; gid = (blk - 76) * 256 + tid; }
  else                { w0 = w0c; b0 = b0c; wp = wpc; bp = bpc; D = 64; gid = (blk - 109) * 256 + tid; }
  if (gid < D * 128) {
    const int d = gid >> 7, c = gid & 127;
    wp[gid] = (c < 64) ? (w0[d * 64 + c] - w0[(D + d) * 64 + c])
                       : w0[(D + d) * 64 + (c - 64)];
  } else if (gid < D * 128 + 128) {
    const int c = gid - D * 128;
    bp[c] = (c < 64) ? b0[c] : 0.f;
  }
}

// ---------------------------------------------------------------- kNN D=64
// Block: 16 rows x 1024 j (jh=blk&1). 256 threads = 8 row-groups (tg) x 32
// lanes (tc). Group tg owns rows {2tg, 2tg+1}; lane tc owns cols
// [tc*16, +16) of each 512-col j-tile. sq[j] computed inline from the staged
// B values (sum over the 8 kb chunks). Metric m = sq[j]-2*dot (row-constant
// sq[i] dropped; same ordering). f32/i32 split top-10, stable strict-<
// insert, exact row-reject threshold (min over 32 lanes), tournament merge.
__global__ __launch_bounds__(256) void knn64_kernel(
    const float* __restrict__ X, int ldx,
    unsigned long long* __restrict__ part /* [T][2][10] */) {
  constexpr int AF = 64 * 16;          // As [k][row]
  constexpr int BF = 8 * 576;          // Bs [k][g16][18], 32 groups
  __shared__ __align__(16) float smem[AF + BF + 576];
  float* As = smem;
  float* Bs = smem + AF;
  float* sqs = smem + AF + BF;         // [g16][18]

  const int tid = threadIdx.x;
  const int blk = blockIdx.x;
  const int b = blk >> 8;              // 256 blocks/graph
  const int rem = blk & 255;
  const int ib = rem >> 1, jh = rem & 1;
  const int i0 = b * NN + ib * 16;
  const int jg0 = b * NN + jh * 1024;
  const int tg = tid >> 5, tc = tid & 31;

  // stage A once: [k][row]
  {
    const int r = tid & 15, kq = tid >> 4;   // kq 0..15 -> k = kq*4..+4
    const float4 v = *(const float4*)&X[(size_t)(i0 + r) * ldx + kq * 4];
    As[(kq * 4 + 0) * 16 + r] = v.x; As[(kq * 4 + 1) * 16 + r] = v.y;
    As[(kq * 4 + 2) * 16 + r] = v.z; As[(kq * 4 + 3) * 16 + r] = v.w;
  }

  const float FINF = __int_as_float(0x7F800000);
  float bk0[KK], bk1[KK]; int bj0[KK], bj1[KK];
#pragma unroll
  for (int s = 0; s < KK; ++s) { bk0[s] = FINF; bj0[s] = 0; bk1[s] = FINF; bj1[s] = 0; }
  float thr0 = FINF, thr1 = FINF, rowThr0 = FINF, rowThr1 = FINF;

  for (int jt = 0; jt < 2; ++jt) {
    const int jtbase = jg0 + jt * 512;
    float acc0[16] = {}, acc1[16] = {};
    float sqa0 = 0.f, sqa1 = 0.f;      // sq accum for staged cols tid, tid+256

    for (int kb = 0; kb < 64; kb += 8) {
      __syncthreads();
#pragma unroll
      for (int h = 0; h < 2; ++h) {
        const int c = tid + h * 256;
        const float* rp = &X[(size_t)(jtbase + c) * ldx + kb];
        const float4 v0 = *(const float4*)rp;
        const float4 v1 = *(const float4*)(rp + 4);
        const int co = (c >> 4) * 18 + (c & 15);
        Bs[0 * 576 + co] = v0.x; Bs[1 * 576 + co] = v0.y;
        Bs[2 * 576 + co] = v0.z; Bs[3 * 576 + co] = v0.w;
        Bs[4 * 576 + co] = v1.x; Bs[5 * 576 + co] = v1.y;
        Bs[6 * 576 + co] = v1.z; Bs[7 * 576 + co] = v1.w;
        float sq = v0.x * v0.x;
        sq = fmaf(v0.y, v0.y, sq); sq = fmaf(v0.z, v0.z, sq);
        sq = fmaf(v0.w, v0.w, sq); sq = fmaf(v1.x, v1.x, sq);
        sq = fmaf(v1.y, v1.y, sq); sq = fmaf(v1.z, v1.z, sq);
        sq = fmaf(v1.w, v1.w, sq);
        if (h == 0) sqa0 += sq; else sqa1 += sq;
        if (kb == 56) sqs[co] = (h == 0) ? sqa0 : sqa1;
      }
      __syncthreads();
#pragma unroll
      for (int kk = 0; kk < 8; ++kk) {
        const float2 av = *(const float2*)&As[(kb + kk) * 16 + 2 * tg];
        const float a0 = av.x, a1 = av.y;
        const float* bp = &Bs[kk * 576 + tc * 18];
#pragma unroll
        for (int c4 = 0; c4 < 4; ++c4) {
          const float4 bv = *(const float4*)(bp + c4 * 4);
          acc0[c4 * 4 + 0] = fmaf(a0, bv.x, acc0[c4 * 4 + 0]);
          acc0[c4 * 4 + 1] = fmaf(a0, bv.y, acc0[c4 * 4 + 1]);
          acc0[c4 * 4 + 2] = fmaf(a0, bv.z, acc0[c4 * 4 + 2]);
          acc0[c4 * 4 + 3] = fmaf(a0, bv.w, acc0[c4 * 4 + 3]);
          acc1[c4 * 4 + 0] = fmaf(a1, bv.x, acc1[c4 * 4 + 0]);
          acc1[c4 * 4 + 1] = fmaf(a1, bv.y, acc1[c4 * 4 + 1]);
          acc1[c4 * 4 + 2] = fmaf(a1, bv.z, acc1[c4 * 4 + 2]);
          acc1[c4 * 4 + 3] = fmaf(a1, bv.w, acc1[c4 * 4 + 3]);
        }
      }
    }

    // selection for tile jt (stable strict-< insert; exact; R8 argument)
#pragma unroll
    for (int c4 = 0; c4 < 4; ++c4) {
      const float4 sv = *(const float4*)&sqs[tc * 18 + c4 * 4];
      const float svv[4] = {sv.x, sv.y, sv.z, sv.w};
#pragma unroll
      for (int u = 0; u < 4; ++u) {
        const int c = c4 * 4 + u;
        const int j = jtbase + tc * 16 + c;
        const float m0 = fmaf(-2.f, acc0[c], svv[u]);
        if (m0 <= rowThr0 && m0 < thr0) {
          bk0[KK - 1] = m0; bj0[KK - 1] = j;
#pragma unroll
          for (int s = KK - 1; s > 0; --s) {
            const bool sw = bk0[s] < bk0[s - 1];
            const float ka = bk0[s - 1], kb2 = bk0[s];
            bk0[s - 1] = sw ? kb2 : ka; bk0[s] = sw ? ka : kb2;
            const int ja = bj0[s - 1], jb2 = bj0[s];
            bj0[s - 1] = sw ? jb2 : ja; bj0[s] = sw ? ja : jb2;
          }
          thr0 = bk0[KK - 1];
        }
        const float m1 = fmaf(-2.f, acc1[c], svv[u]);
        if (m1 <= rowThr1 && m1 < thr1) {
          bk1[KK - 1] = m1; bj1[KK - 1] = j;
#pragma unroll
          for (int s = KK - 1; s > 0; --s) {
            const bool sw = bk1[s] < bk1[s - 1];
            const float ka = bk1[s - 1], kb2 = bk1[s];
            bk1[s - 1] = sw ? kb2 : ka; bk1[s] = sw ? ka : kb2;
            const int ja = bj1[s - 1], jb2 = bj1[s];
            bj1[s - 1] = sw ? jb2 : ja; bj1[s] = sw ? ja : jb2;
          }
          thr1 = bk1[KK - 1];
        }
      }
    }
    float r0 = thr0, r1 = thr1;
#pragma unroll
    for (int d = 1; d < 32; d <<= 1) {
      r0 = fminf(r0, __shfl_xor(r0, d, 64));
      r1 = fminf(r1, __shfl_xor(r1, d, 64));
    }
    rowThr0 = r0; rowThr1 = r1;
  }

  // tournament merge: 10 rounds per row over the 32 tc lanes
#pragma unroll
  for (int s = 0; s < KK; ++s) {
    float w0 = bk0[0];
#pragma unroll
    for (int d = 1; d < 32; d <<= 1) w0 = fminf(w0, __shfl_xor(w0, d, 64));
    int cj0 = (bk0[0] == w0) ? bj0[0] : 0x7FFFFFFF;
#pragma unroll
    for (int d = 1; d < 32; d <<= 1) {
      const int oc = __shfl_xor(cj0, d, 64);
      cj0 = (oc < cj0) ? oc : cj0;
    }
    const bool pop0 = (bk0[0] == w0) && (bj0[0] == cj0);
#pragma unroll
    for (int q = 0; q < KK - 1; ++q) {
      bk0[q] = pop0 ? bk0[q + 1] : bk0[q];
      bj0[q] = pop0 ? bj0[q + 1] : bj0[q];
    }
    if (pop0) bk0[KK - 1] = FINF;
    if (tc == 0)
      part[((size_t)(i0 + 2 * tg) * 2 + jh) * KK + s] =
          ((unsigned long long)fkey(w0) << 32) | (unsigned)cj0;

    float w1 = bk1[0];
#pragma unroll
    for (int d = 1; d < 32; d <<= 1) w1 = fminf(w1, __shfl_xor(w1, d, 64));
    int cj1 = (bk1[0] == w1) ? bj1[0] : 0x7FFFFFFF;
#pragma unroll
    for (int d = 1; d < 32; d <<= 1) {
      const int oc = __shfl_xor(cj1, d, 64);
      cj1 = (oc < cj1) ? oc : cj1;
    }
    const bool pop1 = (bk1[0] == w1) && (bj1[0] == cj1);
#pragma unroll
    for (int q = 0; q < KK - 1; ++q) {
      bk1[q] = pop1 ? bk1[q + 1] : bk1[q];
      bj1[q] = pop1 ? bj1[q + 1] : bj1[q];
    }
    if (pop1) bk1[KK - 1] = FINF;
    if (tc == 1)
      part[((size_t)(i0 + 2 * tg + 1) * 2 + jh) * KK + s] =
          ((unsigned long long)fkey(w1) << 32) | (unsigned)cj1;
  }
}

// ---------------------------------------------------------------- kNN D=6
// R10 structure (16 rows x 1024 j, 1 row per 16-lane group), sq inlined.
__global__ __launch_bounds__(256) void knn6_kernel(
    const float* __restrict__ X,
    unsigned long long* __restrict__ part /* [T][2][10] */) {
  constexpr int AF = 6 * 16;
  constexpr int BF = 6 * 576;          // [k][g32][36]
  __shared__ __align__(16) float smem[AF + BF + 576];
  float* As = smem;
  float* Bs = smem + AF;
  float* sqs = smem + AF + BF;

  const int tid = threadIdx.x;
  const int blk = blockIdx.x;
  const int b = blk >> 8;
  const int rem = blk & 255;
  const int ib = rem >> 1, jh = rem & 1;
  const int i0 = b * NN + ib * 16;
  const int jg0 = b * NN + jh * 1024;
  const int tg = tid >> 4, tc = tid & 15;

  {
    const int r = tid & 15, k = tid >> 4;
    if (k < 6) As[k * 16 + r] = X[(size_t)(i0 + r) * 6 + k];
  }

  const float FINF = __int_as_float(0x7F800000);
  float bk[KK]; int bj[KK];
#pragma unroll
  for (int s = 0; s < KK; ++s) { bk[s] = FINF; bj[s] = 0; }
  float thr = FINF, rowThr = FINF;

  for (int jt = 0; jt < 2; ++jt) {
    const int jtbase = jg0 + jt * 512;
    float acc[32] = {};
    __syncthreads();
#pragma unroll
    for (int h = 0; h < 2; ++h) {
      const int c = tid + h * 256;
      const float* rp = &X[(size_t)(jtbase + c) * 6];
      const int co = (c >> 5) * 36 + (c & 31);
      float sq = 0.f;
#pragma unroll
      for (int k = 0; k < 6; ++k) {
        const float v = rp[k];
        Bs[k * 576 + co] = v;
        sq = fmaf(v, v, sq);
      }
      sqs[co] = sq;
    }
    __syncthreads();
#pragma unroll
    for (int kk = 0; kk < 6; ++kk) {
      const float a0 = As[kk * 16 + tg];
      const float* bp = &Bs[kk * 576 + tc * 36];
#pragma unroll
      for (int c4 = 0; c4 < 8; ++c4) {
        const float4 bv = *(const float4*)(bp + c4 * 4);
        acc[c4 * 4 + 0] = fmaf(a0, bv.x, acc[c4 * 4 + 0]);
        acc[c4 * 4 + 1] = fmaf(a0, bv.y, acc[c4 * 4 + 1]);
        acc[c4 * 4 + 2] = fmaf(a0, bv.z, acc[c4 * 4 + 2]);
        acc[c4 * 4 + 3] = fmaf(a0, bv.w, acc[c4 * 4 + 3]);
      }
    }
#pragma unroll
    for (int c4 = 0; c4 < 8; ++c4) {
      const float4 sv = *(const float4*)&sqs[tc * 36 + c4 * 4];
      const float svv[4] = {sv.x, sv.y, sv.z, sv.w};
#pragma unroll
      for (int u = 0; u < 4; ++u) {
        const int c = c4 * 4 + u;
        const int j = jtbase + tc * 32 + c;
        const float m = fmaf(-2.f, acc[c], svv[u]);
        if (m <= rowThr && m < thr) {
          bk[KK - 1] = m; bj[KK - 1] = j;
#pragma unroll
          for (int s = KK - 1; s > 0; --s) {
            const bool sw = bk[s] < bk[s - 1];
            const float ka = bk[s - 1], kb2 = bk[s];
            bk[s - 1] = sw ? kb2 : ka; bk[s] = sw ? ka : kb2;
            const int ja = bj[s - 1], jb2 = bj[s];
            bj[s - 1] = sw ? jb2 : ja; bj[s] = sw ? ja : jb2;
          }
          thr = bk[KK - 1];
        }
      }
    }
    float r0 = thr;
#pragma unroll
    for (int d = 1; d < 16; d <<= 1) r0 = fminf(r0, __shfl_xor(r0, d, 64));
    rowThr = r0;
  }

  unsigned long long* o = part + ((size_t)(i0 + tg) * 2 + jh) * KK;
#pragma unroll
  for (int s = 0; s < KK; ++s) {
    float w = bk[0];
#pragma unroll
    for (int d = 1; d < 16; d <<= 1) w = fminf(w, __shfl_xor(w, d, 64));
    int cj = (bk[0] == w) ? bj[0] : 0x7FFFFFFF;
#pragma unroll
    for (int d = 1; d < 16; d <<= 1) {
      const int oc = __shfl_xor(cj, d, 64);
      cj = (oc < cj) ? oc : cj;
    }
    const bool pop = (bk[0] == w) && (bj[0] == cj);
#pragma unroll
    for (int q = 0; q < KK - 1; ++q) {
      bk[q] = pop ? bk[q + 1] : bk[q];
      bj[q] = pop ? bj[q + 1] : bj[q];
    }
    if (pop) bk[KK - 1] = FINF;
    if (tc == 0)
      o[s] = ((unsigned long long)fkey(w) << 32) | (unsigned)cj;
  }
}

// final merge of the two j-half partials (20 entries) -> idx
__global__ void knn_merge2_kernel(const unsigned long long* __restrict__ part,
                                  int* __restrict__ idx) {
  const int i = blockIdx.x * blockDim.x + threadIdx.x;
  if (i >= T) return;
  const unsigned long long* p = part + (size_t)i * 2 * KK;
  unsigned long long best[KK];
#pragma unroll
  for (int s = 0; s < KK; ++s) best[s] = ~0ULL;
  for (int q = 0; q < 2 * KK; ++q) {
    const unsigned long long v = p[q];
    if (v < best[KK - 1]) ins10(best, v);
  }
#pragma unroll
  for (int s = 0; s < KK; ++s) idx[i * KK + s] = (int)(best[s] & 0xffffffffu);
}

// node GEMM for D=6 (conv1): hb[t][c] = bp[c] + sum_d x[t][d]*wp[d][c]
__global__ void nodegemm6_kernel(const float* __restrict__ X,
                                 const float* __restrict__ wp,
                                 const float* __restrict__ bp,
                                 float* __restrict__ hb) {
  const int tid = threadIdx.x;
  const int c = tid & 127;
  const int t = blockIdx.x * 2 + (tid >> 7);
  const float* xr = X + (size_t)t * 6;
  float v = bp[c];
#pragma unroll
  for (int d = 0; d < 6; ++d) v = fmaf(xr[d], wp[d * 128 + c], v);
  hb[(size_t)t * 128 + c] = v;
}

// ---------------------------------------------------------------- stat0
__global__ __launch_bounds__(256) void stat0_kernel(
    const float* __restrict__ hb, const int* __restrict__ idx,
    float* __restrict__ stat) {
  const int wv = threadIdx.x >> 6, lane = threadIdx.x & 63;
  const int e0 = (blockIdx.x * 4 + wv) * 16;
  float s1 = 0.f, s2 = 0.f;
  for (int q = 0; q < 16; ++q) {
    const int e = e0 + q;
    const int t = e / 10;
    const int jg = idx[e];
    const float v = fmaxf(hb[(size_t)t * 128 + lane] +
                          hb[(size_t)jg * 128 + 64 + lane], 0.f);
    s1 += v; s2 = fmaf(v, v, s2);
  }
  __shared__ float ls[4][64];
  ls[wv][lane] = s1;
  __syncthreads();
  if (wv == 0) atomicAdd(&stat[lane], ls[0][lane] + ls[1][lane] + ls[2][lane] + ls[3][lane]);
  __syncthreads();
  ls[wv][lane] = s2;
  __syncthreads();
  if (wv == 0) atomicAdd(&stat[1024 + lane], ls[0][lane] + ls[1][lane] + ls[2][lane] + ls[3][lane]);
}

// ---------------------------------------------------------------- BN fold
__global__ void fold_kernel(const float* __restrict__ stat, float cntInv,
                            const float* __restrict__ g, const float* __restrict__ be,
                            const float* __restrict__ W, const float* __restrict__ bias,
                            float* __restrict__ Wf, float* __restrict__ bf,
                            int Cin, int Cout) {
  const int gid = blockIdx.x * blockDim.x + threadIdx.x;
  const int nW = Cin * Cout;
  if (gid < nW) {
    const int d = gid / Cout;
    const float mean = stat[d] * cntInv;
    const float var = fmaf(-mean, mean, stat[1024 + d] * cntInv);
    const float a = g[d] * rsqrtf(var + BN_EPS);
    Wf[gid] = a * W[gid];
  } else if (gid < nW + Cout) {
    const int j = gid - nW;
    float acc = bias[j];
    for (int d = 0; d < Cin; ++d) {
      const float mean = stat[d] * cntInv;
      const float var = fmaf(-mean, mean, stat[1024 + d] * cntInv);
      const float a = g[d] * rsqrtf(var + BN_EPS);
      const float c = fmaf(-mean, a, be[d]);
      acc = fmaf(c, W[d * Cout + j], acc);
    }
    bf[j] = acc;
  }
}

// ---------------------------------------------------------------- mlp1 (node-aligned)
__global__ __launch_bounds__(256) void mlp1n_kernel(
    const float* __restrict__ hb, const int* __restrict__ idx,
    const float* __restrict__ w1f, const float* __restrict__ b1f,
    float* __restrict__ xmax, float* __restrict__ xmin,
    float* __restrict__ stat) {
  __shared__ __align__(16) float As[32 * 164];  // [k][row], 160 + 4 pad
  __shared__ __align__(16) float Bs[32][64];
  __shared__ int ids[160];
  __shared__ float red[16][64];
  const int tid = threadIdx.x;
  const int row0 = blockIdx.x * 160;
  const int tn = tid >> 4, tx = tid & 15;
  if (tid < 160) ids[tid] = idx[row0 + tid];
  float acc[10][4] = {};
  for (int kb = 0; kb < 64; kb += 32) {
    __syncthreads();
    for (int f = tid; f < 160 * 8; f += 256) {
      const int r = f >> 3, q = f & 7;
      const int t = blockIdx.x * 16 + r / 10;
      const int jg = ids[r];
      const float4 va = *(const float4*)&hb[(size_t)t * 128 + kb + q * 4];
      const float4 vb = *(const float4*)&hb[(size_t)jg * 128 + 64 + kb + q * 4];
      As[(q * 4 + 0) * 164 + r] = fmaxf(va.x + vb.x, 0.f);
      As[(q * 4 + 1) * 164 + r] = fmaxf(va.y + vb.y, 0.f);
      As[(q * 4 + 2) * 164 + r] = fmaxf(va.z + vb.z, 0.f);
      As[(q * 4 + 3) * 164 + r] = fmaxf(va.w + vb.w, 0.f);
    }
    {
      const int kr = tid >> 4, c4 = tid & 15;
#pragma unroll
      for (int h = 0; h < 2; ++h) {
        const int k2 = kr + h * 16;
        *(float4*)&Bs[k2][c4 * 4] =
            *(const float4*)&w1f[(size_t)(kb + k2) * 64 + c4 * 4];
      }
    }
    __syncthreads();
#pragma unroll
    for (int k = 0; k < 32; ++k) {
      const float* ap = &As[k * 164 + tn * 10];
      const float4 bv = *(const float4*)&Bs[k][tx * 4];
#pragma unroll
      for (int i = 0; i < 10; ++i) {
        const float a = ap[i];
        acc[i][0] = fmaf(a, bv.x, acc[i][0]);
        acc[i][1] = fmaf(a, bv.y, acc[i][1]);
        acc[i][2] = fmaf(a, bv.z, acc[i][2]);
        acc[i][3] = fmaf(a, bv.w, acc[i][3]);
      }
    }
  }
  const int node = blockIdx.x * 16 + tn;
  float s2v[4];
#pragma unroll
  for (int j = 0; j < 4; ++j) {
    const float bj = b1f[tx * 4 + j];
    float mx = -3.4e38f, mn = 3.4e38f, s1 = 0.f, s2 = 0.f;
#pragma unroll
    for (int i = 0; i < 10; ++i) {
      const float v = fmaxf(acc[i][j] + bj, 0.f);
      mx = fmaxf(mx, v); mn = fminf(mn, v);
      s1 += v; s2 = fmaf(v, v, s2);
    }
    xmax[(size_t)node * 64 + tx * 4 + j] = mx;
    xmin[(size_t)node * 64 + tx * 4 + j] = mn;
    red[tn][tx * 4 + j] = s1;
    s2v[j] = s2;
  }
  __syncthreads();
  if (tid < 64) {
    float s = 0.f;
#pragma unroll
    for (int q = 0; q < 16; ++q) s += red[q][tid];
    atomicAdd(&stat[tid], s);
  }
  __syncthreads();
#pragma unroll
  for (int j = 0; j < 4; ++j) red[tn][tx * 4 + j] = s2v[j];
  __syncthreads();
  if (tid < 64) {
    float s = 0.f;
#pragma unroll
    for (int q = 0; q < 16; ++q) s += red[q][tid];
    atomicAdd(&stat[1024 + tid], s);
  }
}

// ---------------------------------------------------------------- conv output
__global__ void conv_out_kernel(const float* __restrict__ xmax, const float* __restrict__ xmin,
                                const float* __restrict__ stat, float cntInv,
                                const float* __restrict__ g, const float* __restrict__ be,
                                float* __restrict__ cat, int coff) {
  const int gid = blockIdx.x * blockDim.x + threadIdx.x;
  const int c = gid & 63, t = gid >> 6;
  const float mean = stat[c] * cntInv;
  const float var = fmaf(-mean, mean, stat[1024 + c] * cntInv);
  const float a = g[c] * rsqrtf(var + BN_EPS);
  const float cc = fmaf(-mean, a, be[c]);
  const float v = (a >= 0.f) ? fmaf(a, xmax[gid], cc) : fmaf(a, xmin[gid], cc);
  cat[(size_t)t * 192 + coff + c] = v;
}

// ---------------------------------------------------------------- generic GEMM
__global__ __launch_bounds__(256) void gemm_kernel(
    const float* __restrict__ A, int lda,
    const float* __restrict__ Bw, int ldb,
    const float* __restrict__ bias, int biasPerGraph,
    float* __restrict__ C,
    float* __restrict__ stat,
    unsigned* __restrict__ cmax, unsigned* __restrict__ cmin,
    int Kdim, int Ncols, int doRelu) {
  __shared__ float As[32][68];
  __shared__ float Bs[32][64];
  const int tid = threadIdx.x;
  const int nbx = Ncols >> 6;
  const int bx = blockIdx.x % nbx, by = blockIdx.x / nbx;
  const int row0 = by << 6, col0 = bx << 6;
  const int tx = tid & 15, ty = tid >> 4;
  float acc[4][4] = {};
  for (int kb = 0; kb < Kdim; kb += 32) {
    __syncthreads();
    {
      const int r = tid >> 3, fc = tid & 7;
#pragma unroll
      for (int h = 0; h < 2; ++h) {
        const int rr = r + h * 32;
        const float4 va = *(const float4*)&A[(size_t)(row0 + rr) * lda + kb + fc * 4];
        As[fc * 4 + 0][rr] = va.x; As[fc * 4 + 1][rr] = va.y;
        As[fc * 4 + 2][rr] = va.z; As[fc * 4 + 3][rr] = va.w;
      }
      const int kr = tid >> 4, c4 = tid & 15;
#pragma unroll
      for (int h = 0; h < 2; ++h) {
        const int k2 = kr + h * 16;
        *(float4*)&Bs[k2][c4 * 4] =
            *(const float4*)&Bw[(size_t)(kb + k2) * ldb + col0 + c4 * 4];
      }
    }
    __syncthreads();
#pragma unroll
    for (int k = 0; k < 32; ++k) {
      const float4 av = *(const float4*)&As[k][ty * 4];
      const float4 bv = *(const float4*)&Bs[k][tx * 4];
      const float a4[4] = {av.x, av.y, av.z, av.w};
      const float b4[4] = {bv.x, bv.y, bv.z, bv.w};
#pragma unroll
      for (int i = 0; i < 4; ++i)
#pragma unroll
        for (int j = 0; j < 4; ++j) acc[i][j] = fmaf(a4[i], b4[j], acc[i][j]);
    }
  }
  const int graph = row0 >> 11;
  const float* bp = bias + (biasPerGraph ? graph * Ncols : 0) + col0 + tx * 4;
  float v[4][4];
#pragma unroll
  for (int j = 0; j < 4; ++j) {
    const float bj = bp[j];
#pragma unroll
    for (int i = 0; i < 4; ++i) {
      const float s = acc[i][j] + bj;
      v[i][j] = doRelu ? fmaxf(s, 0.f) : s;
    }
  }
  if (C) {
#pragma unroll
    for (int i = 0; i < 4; ++i) {
      const float4 st = make_float4(v[i][0], v[i][1], v[i][2], v[i][3]);
      *(float4*)&C[(size_t)(row0 + ty * 4 + i) * Ncols + col0 + tx * 4] = st;
    }
  }
  if (stat) {
    __syncthreads();
#pragma unroll
    for (int j = 0; j < 4; ++j)
      As[ty][tx * 4 + j] = v[0][j] + v[1][j] + v[2][j] + v[3][j];
    __syncthreads();
    if (tid < 64) {
      float s = 0.f;
#pragma unroll
      for (int q = 0; q < 16; ++q) s += As[q][tid];
      atomicAdd(&stat[col0 + tid], s);
    }
    __syncthreads();
#pragma unroll
    for (int j = 0; j < 4; ++j) {
      float s = 0.f;
#pragma unroll
      for (int i = 0; i < 4; ++i) s = fmaf(v[i][j], v[i][j], s);
      As[ty][tx * 4 + j] = s;
    }
    __syncthreads();
    if (tid < 64) {
      float s = 0.f;
#pragma unroll
      for (int q = 0; q < 16; ++q) s += As[q][tid];
      atomicAdd(&stat[1024 + col0 + tid], s);
    }
    if (cmax) {
      __syncthreads();
#pragma unroll
      for (int j = 0; j < 4; ++j)
        As[ty][tx * 4 + j] = fmaxf(fmaxf(v[0][j], v[1][j]), fmaxf(v[2][j], v[3][j]));
      __syncthreads();
      if (tid < 64) {
        float s = As[0][tid];
#pragma unroll
        for (int q = 1; q < 16; ++q) s = fmaxf(s, As[q][tid]);
        atomicMax(&cmax[graph * Ncols + col0 + tid], fkey(s));
      }
      __syncthreads();
#pragma unroll
      for (int j = 0; j < 4; ++j)
        As[ty][tx * 4 + j] = fminf(fminf(v[0][j], v[1][j]), fminf(v[2][j], v[3][j]));
      __syncthreads();
      if (tid < 64) {
        float s = As[0][tid];
#pragma unroll
        for (int q = 1; q < 16; ++q) s = fminf(s, As[q][tid]);
        atomicMin(&cmin[graph * Ncols + col0 + tid], fkey(s));
      }
    }
  }
}

// ---------------------------------------------------------------- pooled (normalized)
__global__ void pool_finalize_kernel(const unsigned* __restrict__ cmax,
                                     const unsigned* __restrict__ cmin,
                                     const float* __restrict__ stat, float cntInv,
                                     const float* __restrict__ g, const float* __restrict__ be,
                                     float* __restrict__ pooled) {
  const int gid = blockIdx.x * blockDim.x + threadIdx.x;
  if (gid >= NBG * 1024) return;
  const int col = gid & 1023;
  const float mean = stat[col] * cntInv;
  const float var = fmaf(-mean, mean, stat[1024 + col] * cntInv);
  const float a = g[col] * rsqrtf(var + BN_EPS);
  const float cc = fmaf(-mean, a, be[col]);
  const float fx = funkey(cmax[gid]), fn = funkey(cmin[gid]);
  pooled[gid] = (a >= 0.f) ? fmaf(a, fx, cc) : fmaf(a, fn, cc);
}

// po[b][j] = m0_b[j] + pooled[b] @ m0_w[192:1216]
__global__ void po_gemm_kernel(const float* __restrict__ pooled,
                               const float* __restrict__ w2,
                               const float* __restrict__ m0b,
                               float* __restrict__ po) {
  const int b = blockIdx.x, j = threadIdx.x;
  const float* pr = pooled + b * 1024;
  float a0 = m0b[j], a1 = 0.f, a2 = 0.f, a3 = 0.f;
  for (int d = 0; d < 1024; d += 4) {
    a0 = fmaf(pr[d + 0], w2[(size_t)(d + 0) * 256 + j], a0);
    a1 = fmaf(pr[d + 1], w2[(size_t)(d + 1) * 256 + j], a1);
    a2 = fmaf(pr[d + 2], w2[(size_t)(d + 2) * 256 + j], a2);
    a3 = fmaf(pr[d + 3], w2[(size_t)(d + 3) * 256 + j], a3);
  }
  po[b * 256 + j] = (a0 + a1) + (a2 + a3);
}

// out[t] = hm1[t] @ m2f + b2f
__global__ __launch_bounds__(256) void m2_gemv_kernel(
    const float* __restrict__ hm1, const float* __restrict__ m2f,
    const float* __restrict__ m2fb, float* __restrict__ out) {
  const int wv = threadIdx.x >> 6, lane = threadIdx.x & 63;
  const int t = blockIdx.x * 4 + wv;
  const float* r = hm1 + (size_t)t * 128;
  float v = fmaf(r[lane], m2f[lane], r[64 + lane] * m2f[64 + lane]);
  for (int off = 32; off; off >>= 1) v += __shfl_down(v, off);
  if (lane == 0) out[t] = v + m2fb[0];
}

// ---------------------------------------------------------------------------
extern "C" void kernel_launch(void* const* d_in, const int* in_sizes, int n_in,
                              void* d_out, int out_size, void* d_ws, size_t ws_size,
                              hipStream_t stream) {
  const float* x = (const float*)d_in[0];
  const float* c_w0[3] = {(const float*)d_in[1], (const float*)d_in[9],  (const float*)d_in[17]};
  const float* c_b0[3] = {(const float*)d_in[2], (const float*)d_in[10], (const float*)d_in[18]};
  const float* c_g0[3] = {(const float*)d_in[3], (const float*)d_in[11], (const float*)d_in[19]};
  const float* c_be0[3]= {(const float*)d_in[4], (const float*)d_in[12], (const float*)d_in[20]};
  const float* c_w1[3] = {(const float*)d_in[5], (const float*)d_in[13], (const float*)d_in[21]};
  const float* c_b1[3] = {(const float*)d_in[6], (const float*)d_in[14], (const float*)d_in[22]};
  const float* c_g1[3] = {(const float*)d_in[7], (const float*)d_in[15], (const float*)d_in[23]};
  const float* c_be1[3]= {(const float*)d_in[8], (const float*)d_in[16], (const float*)d_in[24]};
  const float* l1_w = (const float*)d_in[25];
  const float* l1_b = (const float*)d_in[26];
  const float* l1_g = (const float*)d_in[27];
  const float* l1_be= (const float*)d_in[28];
  const float* m0_w = (const float*)d_in[29];
  const float* m0_b = (const float*)d_in[30];
  const float* m0_g = (const float*)d_in[31];
  const float* m0_be= (const float*)d_in[32];
  const float* m1_w = (const float*)d_in[33];
  const float* m1_b = (const float*)d_in[34];
  const float* m1_g = (const float*)d_in[35];
  const float* m1_be= (const float*)d_in[36];
  const float* m2_w = (const float*)d_in[37];
  const float* m2_b = (const float*)d_in[38];
  float* out = (float*)d_out;

  char* ws = (char*)d_ws;
  float*    stats  = (float*)(ws + 0);
  unsigned* cmax   = (unsigned*)(ws + 73728);
  unsigned* cmin   = (unsigned*)(ws + 106496);
  float*    pooled = (float*)(ws + 139264);
  float*    po     = (float*)(ws + 172032);
  float*    w1f    = (float*)(ws + 180224);
  float*    b1f    = (float*)(ws + 196608);
  float*    m1f    = (float*)(ws + 196864);
  float*    m1fb   = (float*)(ws + 327936);
  float*    m2f    = (float*)(ws + 328448);
  float*    m2fb   = (float*)(ws + 328960);
  int*      idx    = (int*)  (ws + 394752);     // [T][10]
  float*    xmax   = (float*)(ws + 1050112);    // [T][64]
  float*    xmin   = (float*)(ws + 5244416);    // [T][64]
  float*    cat    = (float*)(ws + 9438720);    // [T][192]
  float*    wp[3]  = {(float*)(ws + 22021632),
                      (float*)(ws + 22025216),
                      (float*)(ws + 22058496)};
  float*    bp[3]  = {(float*)(ws + 22024704), (float*)(ws + 22057984),
                      (float*)(ws + 22091264)};
  char*     regA   = ws + 22091776;
  unsigned long long* part = (unsigned long long*)regA;   // [T][2][10]
  float*    hb     = (float*)(regA + 2621440);  // [T][128] (conv phase)
  float*    hm0    = (float*)regA;              // [T][256] (post-conv)
  float*    hm1    = (float*)(regA + 16777216); // [T][128] (post-conv)

  const float cInvE = 1.f / (float)(T * KK);
  const float cInvT = 1.f / (float)T;

  prep_kernel<<<142, 256, 0, stream>>>(stats, cmax, cmin,
                                       c_w0[0], c_b0[0], c_w0[1], c_b0[1], c_w0[2], c_b0[2],
                                       wp[0], bp[0], wp[1], bp[1], wp[2], bp[2]);

  for (int cidx = 0; cidx < 3; ++cidx) {
    const float* Xin; int ldx, Din;
    const int coff = cidx * 64;
    if (cidx == 0) { Xin = x; ldx = 6; Din = 6; }
    else { Xin = cat + (cidx - 1) * 64; ldx = 192; Din = 64; }
    float* st0 = stats + (cidx * 2) * 2048;
    float* st1 = stats + (cidx * 2 + 1) * 2048;

    if (Din == 6)
      knn6_kernel<<<2048, 256, 0, stream>>>(Xin, part);
    else
      knn64_kernel<<<2048, 256, 0, stream>>>(Xin, ldx, part);
    knn_merge2_kernel<<<T / 256, 256, 0, stream>>>(part, idx);
    if (Din == 6)
      nodegemm6_kernel<<<T / 2, 256, 0, stream>>>(Xin, wp[0], bp[0], hb);
    else
      gemm_kernel<<<(T / 64) * 2, 256, 0, stream>>>(
          Xin, ldx, wp[cidx], 128, bp[cidx], 0, hb,
          nullptr, nullptr, nullptr, 64, 128, 0);
    stat0_kernel<<<T * KK / 64, 256, 0, stream>>>(hb, idx, st0);
    fold_kernel<<<17, 256, 0, stream>>>(st0, cInvE, c_g0[cidx], c_be0[cidx],
                                        c_w1[cidx], c_b1[cidx], w1f, b1f, 64, 64);
    mlp1n_kernel<<<T * KK / 160, 256, 0, stream>>>(hb, idx, w1f, b1f,
                                                   xmax, xmin, st1);
    conv_out_kernel<<<T * 64 / 256, 256, 0, stream>>>(xmax, xmin, st1, cInvE,
                                                      c_g1[cidx], c_be1[cidx], cat, coff);
  }

  float* stl1 = stats + 6 * 2048;
  gemm_kernel<<<(T / 64) * (1024 / 64), 256, 0, stream>>>(
      cat, 192, l1_w, 1024, l1_b, 0, nullptr, stl1, cmax, cmin, 192, 1024, 1);
  pool_finalize_kernel<<<32, 256, 0, stream>>>(cmax, cmin, stl1, cInvT, l1_g, l1_be, pooled);
  po_gemm_kernel<<<8, 256, 0, stream>>>(pooled, m0_w + 192 * 256, m0_b, po);

  float* stm0 = stats + 7 * 2048;
  gemm_kernel<<<(T / 64) * (256 / 64), 256, 0, stream>>>(
      cat, 192, m0_w, 256, po, 1, hm0, stm0, nullptr, nullptr, 192, 256, 1);
  fold_kernel<<<129, 256, 0, stream>>>(stm0, cInvT, m0_g, m0_be, m1_w, m1_b, m1f, m1fb, 256, 128);

  float* stm1 = stats + 8 * 2048;
  gemm_kernel<<<(T / 64) * (128 / 64), 256, 0, stream>>>(
      hm0, 256, m1f, 128, m1fb, 0, hm1, stm1, nullptr, nullptr, 256, 128, 1);
  fold_kernel<<<1, 256, 0, stream>>>(stm1, cInvT, m1_g, m1_be, m2_w, m2_b, m2f, m2fb, 128, 1);
  m2_gemv_kernel<<<T / 4, 256, 0, stream>>>(hm1, m2f, m2fb, out);
}

// Round 14
// 1901.330 us; speedup vs baseline: 1.0602x; 1.0602x over previous
//
#include <hip/hip_runtime.h>
#include <stdint.h>

// ---------------------------------------------------------------------------
// DGCNN forward on MI355X. All fp32. B=8 graphs x N=2048 nodes, D0=6, K=10.
// BN folded into following layer weights; max-pools on raw activations via
// monotone-affine trick; x5 branch of m0 reduced to [8,1024]@[1024,256].
// R13: DETERMINISM FIX — all float atomicAdd BN-stat accumulation replaced by
// per-block partial stores (spart[blk][128]) + fixed-order statredN reduce.
// Float-atomic ordering noise was amplified by the cat->kNN near-tie path
// into ~0.6 output jumps across graph replays (R12 tripwire). uint max/min
// pooling atomics are exactly associative and stay. Perf structure = R12.
// ---------------------------------------------------------------------------

constexpr int T  = 16384;   // total nodes
constexpr int NBG = 8;      // graphs
constexpr int NN = 2048;    // nodes per graph
constexpr int KK = 10;      // kNN
constexpr float BN_EPS = 1e-5f;

__device__ __forceinline__ unsigned fkey(float f) {
  unsigned u = __float_as_uint(f);
  return (u & 0x80000000u) ? ~u : (u | 0x80000000u);
}
__device__ __forceinline__ float funkey(unsigned k) {
  unsigned u = (k & 0x80000000u) ? (k ^ 0x80000000u) : ~k;
  return __uint_as_float(u);
}

__device__ __forceinline__ void ins10(unsigned long long (&b)[KK],
                                      unsigned long long v) {
  b[KK - 1] = v;
#pragma unroll
  for (int s = KK - 1; s > 0; --s)
    if (b[s] < b[s - 1]) {
      unsigned long long t2 = b[s]; b[s] = b[s - 1]; b[s - 1] = t2;
    }
}

// ---------------------------------------------------------------- prep
__global__ void prep_kernel(float* __restrict__ stats,
                            unsigned* __restrict__ cmax, unsigned* __restrict__ cmin,
                            const float* __restrict__ w0a, const float* __restrict__ b0a,
                            const float* __restrict__ w0b, const float* __restrict__ b0b,
                            const float* __restrict__ w0c, const float* __restrict__ b0c,
                            float* __restrict__ wpa, float* __restrict__ bpa,
                            float* __restrict__ wpb, float* __restrict__ bpb,
                            float* __restrict__ wpc, float* __restrict__ bpc) {
  const int blk = blockIdx.x, tid = threadIdx.x;
  if (blk < 72) {
    const int gid = blk * 256 + tid;
    if (gid < 9 * 2048) stats[gid] = 0.f;
    if (gid < NBG * 1024) { cmax[gid] = 0u; cmin[gid] = 0xFFFFFFFFu; }
    return;
  }
  const float* w0; const float* b0; float* wp; float* bp; int D, gid;
  if (blk < 76)       { w0 = w0a; b0 = b0a; wp = wpa; bp = bpa; D = 6;  gid = (blk - 72) * 256 + tid; }
  else if (blk < 109) { w0 = w0b; b0 = b0b; wp = wpb; bp = bpb; D = 64; gid = (blk - 76) * 256 + tid; }
  else                { w0 = w0c; b0 = b0c; wp = wpc; bp = bpc; D = 64; gid = (blk - 109) * 256 + tid; }
  if (gid < D * 128) {
    const int d = gid >> 7, c = gid & 127;
    wp[gid] = (c < 64) ? (w0[d * 64 + c] - w0[(D + d) * 64 + c])
                       : w0[(D + d) * 64 + (c - 64)];
  } else if (gid < D * 128 + 128) {
    const int c = gid - D * 128;
    bp[c] = (c < 64) ? b0[c] : 0.f;
  }
}

// ---------------------------------------------------------------- stat reduce
// Deterministic fixed-order reduce of per-block partials.
// part[p][128] for column-block bx at p = by*nbx + bx; thread t<64 -> sum,
// t>=64 -> sumsq. Writes stat[bx*64 + c] / stat[1024 + bx*64 + c].
__global__ void statredN_kernel(const float* __restrict__ part, int nby, int nbx,
                                float* __restrict__ stat) {
  const int t = threadIdx.x;      // 128
  const int bx = blockIdx.x;
  float s0 = 0.f, s1 = 0.f, s2 = 0.f, s3 = 0.f;
  int by = 0;
  for (; by + 4 <= nby; by += 4) {
    s0 += part[(size_t)((by + 0) * nbx + bx) * 128 + t];
    s1 += part[(size_t)((by + 1) * nbx + bx) * 128 + t];
    s2 += part[(size_t)((by + 2) * nbx + bx) * 128 + t];
    s3 += part[(size_t)((by + 3) * nbx + bx) * 128 + t];
  }
  for (; by < nby; ++by) s0 += part[(size_t)(by * nbx + bx) * 128 + t];
  const float s = (s0 + s1) + (s2 + s3);
  if (t < 64) stat[bx * 64 + t] = s;
  else        stat[1024 + bx * 64 + (t - 64)] = s;
}

// ---------------------------------------------------------------- kNN D=64
// R10 tile: block = 32 rows x 1024 j (jh=blk&1). 256 threads = 16 groups
// (tg) x 16 lanes (tc); group owns rows {2tg,2tg+1}, lane owns cols
// [tc*32,+32). Bs [k][g32][36] (144 B stride, 16B-aligned, conflict-free).
// sq computed inline from staged B. Stable strict-< insert + exact row-reject
// threshold + tournament merge -> part[T][2][10].
__global__ __launch_bounds__(256) void knn64_kernel(
    const float* __restrict__ X, int ldx,
    unsigned long long* __restrict__ part /* [T][2][10] */) {
  constexpr int AF = 64 * 32;
  constexpr int BF = 8 * 576;
  __shared__ __align__(16) float smem[AF + BF + 576];
  float* As = smem;
  float* Bs = smem + AF;
  float* sqs = smem + AF + BF;

  const int tid = threadIdx.x;
  const int blk = blockIdx.x;
  const int b = blk >> 7;
  const int rem = blk & 127;
  const int ib = rem >> 1, jh = rem & 1;
  const int i0 = b * NN + ib * 32;
  const int jg0 = b * NN + jh * 1024;
  const int tg = tid >> 4, tc = tid & 15;

  {
    const int r = tid & 31, ks = (tid >> 5) * 8;
    const float* rp = &X[(size_t)(i0 + r) * ldx + ks];
    const float4 v0 = *(const float4*)rp;
    const float4 v1 = *(const float4*)(rp + 4);
    As[(ks + 0) * 32 + r] = v0.x; As[(ks + 1) * 32 + r] = v0.y;
    As[(ks + 2) * 32 + r] = v0.z; As[(ks + 3) * 32 + r] = v0.w;
    As[(ks + 4) * 32 + r] = v1.x; As[(ks + 5) * 32 + r] = v1.y;
    As[(ks + 6) * 32 + r] = v1.z; As[(ks + 7) * 32 + r] = v1.w;
  }

  const float FINF = __int_as_float(0x7F800000);
  float bk0[KK], bk1[KK]; int bj0[KK], bj1[KK];
#pragma unroll
  for (int s = 0; s < KK; ++s) { bk0[s] = FINF; bj0[s] = 0; bk1[s] = FINF; bj1[s] = 0; }
  float thr0 = FINF, thr1 = FINF, rowThr0 = FINF, rowThr1 = FINF;

  for (int jt = 0; jt < 2; ++jt) {
    const int jtbase = jg0 + jt * 512;
    float acc0[32] = {}, acc1[32] = {};
    float sqa0 = 0.f, sqa1 = 0.f;

    for (int kb = 0; kb < 64; kb += 8) {
      __syncthreads();
#pragma unroll
      for (int h = 0; h < 2; ++h) {
        const int c = tid + h * 256;
        const float* rp = &X[(size_t)(jtbase + c) * ldx + kb];
        const float4 v0 = *(const float4*)rp;
        const float4 v1 = *(const float4*)(rp + 4);
        const int co = (c >> 5) * 36 + (c & 31);
        Bs[0 * 576 + co] = v0.x; Bs[1 * 576 + co] = v0.y;
        Bs[2 * 576 + co] = v0.z; Bs[3 * 576 + co] = v0.w;
        Bs[4 * 576 + co] = v1.x; Bs[5 * 576 + co] = v1.y;
        Bs[6 * 576 + co] = v1.z; Bs[7 * 576 + co] = v1.w;
        float sq = v0.x * v0.x;
        sq = fmaf(v0.y, v0.y, sq); sq = fmaf(v0.z, v0.z, sq);
        sq = fmaf(v0.w, v0.w, sq); sq = fmaf(v1.x, v1.x, sq);
        sq = fmaf(v1.y, v1.y, sq); sq = fmaf(v1.z, v1.z, sq);
        sq = fmaf(v1.w, v1.w, sq);
        if (h == 0) sqa0 += sq; else sqa1 += sq;
        if (kb == 56) sqs[co] = (h == 0) ? sqa0 : sqa1;
      }
      __syncthreads();
#pragma unroll
      for (int kk = 0; kk < 8; ++kk) {
        const float2 av = *(const float2*)&As[(kb + kk) * 32 + 2 * tg];
        const float a0 = av.x, a1 = av.y;
        const float* bp = &Bs[kk * 576 + tc * 36];
#pragma unroll
        for (int c4 = 0; c4 < 8; ++c4) {
          const float4 bv = *(const float4*)(bp + c4 * 4);
          acc0[c4 * 4 + 0] = fmaf(a0, bv.x, acc0[c4 * 4 + 0]);
          acc0[c4 * 4 + 1] = fmaf(a0, bv.y, acc0[c4 * 4 + 1]);
          acc0[c4 * 4 + 2] = fmaf(a0, bv.z, acc0[c4 * 4 + 2]);
          acc0[c4 * 4 + 3] = fmaf(a0, bv.w, acc0[c4 * 4 + 3]);
          acc1[c4 * 4 + 0] = fmaf(a1, bv.x, acc1[c4 * 4 + 0]);
          acc1[c4 * 4 + 1] = fmaf(a1, bv.y, acc1[c4 * 4 + 1]);
          acc1[c4 * 4 + 2] = fmaf(a1, bv.z, acc1[c4 * 4 + 2]);
          acc1[c4 * 4 + 3] = fmaf(a1, bv.w, acc1[c4 * 4 + 3]);
        }
      }
    }

    // selection (stable strict-< insert; exact; R8 argument)
#pragma unroll
    for (int c4 = 0; c4 < 8; ++c4) {
      const float4 sv = *(const float4*)&sqs[tc * 36 + c4 * 4];
      const float svv[4] = {sv.x, sv.y, sv.z, sv.w};
#pragma unroll
      for (int u = 0; u < 4; ++u) {
        const int c = c4 * 4 + u;
        const int j = jtbase + tc * 32 + c;
        const float m0 = fmaf(-2.f, acc0[c], svv[u]);
        if (m0 <= rowThr0 && m0 < thr0) {
          bk0[KK - 1] = m0; bj0[KK - 1] = j;
#pragma unroll
          for (int s = KK - 1; s > 0; --s) {
            const bool sw = bk0[s] < bk0[s - 1];
            const float ka = bk0[s - 1], kb2 = bk0[s];
            bk0[s - 1] = sw ? kb2 : ka; bk0[s] = sw ? ka : kb2;
            const int ja = bj0[s - 1], jb2 = bj0[s];
            bj0[s - 1] = sw ? jb2 : ja; bj0[s] = sw ? ja : jb2;
          }
          thr0 = bk0[KK - 1];
        }
        const float m1 = fmaf(-2.f, acc1[c], svv[u]);
        if (m1 <= rowThr1 && m1 < thr1) {
          bk1[KK - 1] = m1; bj1[KK - 1] = j;
#pragma unroll
          for (int s = KK - 1; s > 0; --s) {
            const bool sw = bk1[s] < bk1[s - 1];
            const float ka = bk1[s - 1], kb2 = bk1[s];
            bk1[s - 1] = sw ? kb2 : ka; bk1[s] = sw ? ka : kb2;
            const int ja = bj1[s - 1], jb2 = bj1[s];
            bj1[s - 1] = sw ? jb2 : ja; bj1[s] = sw ? ja : jb2;
          }
          thr1 = bk1[KK - 1];
        }
      }
    }
    float r0 = thr0, r1 = thr1;
#pragma unroll
    for (int d = 1; d < 16; d <<= 1) {
      r0 = fminf(r0, __shfl_xor(r0, d, 64));
      r1 = fminf(r1, __shfl_xor(r1, d, 64));
    }
    rowThr0 = r0; rowThr1 = r1;
  }

  // tournament merge: 10 rounds per row over the 16 tc lanes
#pragma unroll
  for (int s = 0; s < KK; ++s) {
    float w0 = bk0[0];
#pragma unroll
    for (int d = 1; d < 16; d <<= 1) w0 = fminf(w0, __shfl_xor(w0, d, 64));
    int cj0 = (bk0[0] == w0) ? bj0[0] : 0x7FFFFFFF;
#pragma unroll
    for (int d = 1; d < 16; d <<= 1) {
      const int oc = __shfl_xor(cj0, d, 64);
      cj0 = (oc < cj0) ? oc : cj0;
    }
    const bool pop0 = (bk0[0] == w0) && (bj0[0] == cj0);
#pragma unroll
    for (int q = 0; q < KK - 1; ++q) {
      bk0[q] = pop0 ? bk0[q + 1] : bk0[q];
      bj0[q] = pop0 ? bj0[q + 1] : bj0[q];
    }
    if (pop0) bk0[KK - 1] = FINF;
    if (tc == 0)
      part[((size_t)(i0 + 2 * tg) * 2 + jh) * KK + s] =
          ((unsigned long long)fkey(w0) << 32) | (unsigned)cj0;

    float w1 = bk1[0];
#pragma unroll
    for (int d = 1; d < 16; d <<= 1) w1 = fminf(w1, __shfl_xor(w1, d, 64));
    int cj1 = (bk1[0] == w1) ? bj1[0] : 0x7FFFFFFF;
#pragma unroll
    for (int d = 1; d < 16; d <<= 1) {
      const int oc = __shfl_xor(cj1, d, 64);
      cj1 = (oc < cj1) ? oc : cj1;
    }
    const bool pop1 = (bk1[0] == w1) && (bj1[0] == cj1);
#pragma unroll
    for (int q = 0; q < KK - 1; ++q) {
      bk1[q] = pop1 ? bk1[q + 1] : bk1[q];
      bj1[q] = pop1 ? bj1[q + 1] : bj1[q];
    }
    if (pop1) bk1[KK - 1] = FINF;
    if (tc == 1)
      part[((size_t)(i0 + 2 * tg + 1) * 2 + jh) * KK + s] =
          ((unsigned long long)fkey(w1) << 32) | (unsigned)cj1;
  }
}

// ---------------------------------------------------------------- kNN D=6
__global__ __launch_bounds__(256) void knn6_kernel(
    const float* __restrict__ X,
    unsigned long long* __restrict__ part /* [T][2][10] */) {
  constexpr int AF = 6 * 16;
  constexpr int BF = 6 * 576;
  __shared__ __align__(16) float smem[AF + BF + 576];
  float* As = smem;
  float* Bs = smem + AF;
  float* sqs = smem + AF + BF;

  const int tid = threadIdx.x;
  const int blk = blockIdx.x;
  const int b = blk >> 8;
  const int rem = blk & 255;
  const int ib = rem >> 1, jh = rem & 1;
  const int i0 = b * NN + ib * 16;
  const int jg0 = b * NN + jh * 1024;
  const int tg = tid >> 4, tc = tid & 15;

  {
    const int r = tid & 15, k = tid >> 4;
    if (k < 6) As[k * 16 + r] = X[(size_t)(i0 + r) * 6 + k];
  }

  const float FINF = __int_as_float(0x7F800000);
  float bk[KK]; int bj[KK];
#pragma unroll
  for (int s = 0; s < KK; ++s) { bk[s] = FINF; bj[s] = 0; }
  float thr = FINF, rowThr = FINF;

  for (int jt = 0; jt < 2; ++jt) {
    const int jtbase = jg0 + jt * 512;
    float acc[32] = {};
    __syncthreads();
#pragma unroll
    for (int h = 0; h < 2; ++h) {
      const int c = tid + h * 256;
      const float* rp = &X[(size_t)(jtbase + c) * 6];
      const int co = (c >> 5) * 36 + (c & 31);
      float sq = 0.f;
#pragma unroll
      for (int k = 0; k < 6; ++k) {
        const float v = rp[k];
        Bs[k * 576 + co] = v;
        sq = fmaf(v, v, sq);
      }
      sqs[co] = sq;
    }
    __syncthreads();
#pragma unroll
    for (int kk = 0; kk < 6; ++kk) {
      const float a0 = As[kk * 16 + tg];
      const float* bp = &Bs[kk * 576 + tc * 36];
#pragma unroll
      for (int c4 = 0; c4 < 8; ++c4) {
        const float4 bv = *(const float4*)(bp + c4 * 4);
        acc[c4 * 4 + 0] = fmaf(a0, bv.x, acc[c4 * 4 + 0]);
        acc[c4 * 4 + 1] = fmaf(a0, bv.y, acc[c4 * 4 + 1]);
        acc[c4 * 4 + 2] = fmaf(a0, bv.z, acc[c4 * 4 + 2]);
        acc[c4 * 4 + 3] = fmaf(a0, bv.w, acc[c4 * 4 + 3]);
      }
    }
#pragma unroll
    for (int c4 = 0; c4 < 8; ++c4) {
      const float4 sv = *(const float4*)&sqs[tc * 36 + c4 * 4];
      const float svv[4] = {sv.x, sv.y, sv.z, sv.w};
#pragma unroll
      for (int u = 0; u < 4; ++u) {
        const int c = c4 * 4 + u;
        const int j = jtbase + tc * 32 + c;
        const float m = fmaf(-2.f, acc[c], svv[u]);
        if (m <= rowThr && m < thr) {
          bk[KK - 1] = m; bj[KK - 1] = j;
#pragma unroll
          for (int s = KK - 1; s > 0; --s) {
            const bool sw = bk[s] < bk[s - 1];
            const float ka = bk[s - 1], kb2 = bk[s];
            bk[s - 1] = sw ? kb2 : ka; bk[s] = sw ? ka : kb2;
            const int ja = bj[s - 1], jb2 = bj[s];
            bj[s - 1] = sw ? jb2 : ja; bj[s] = sw ? ja : jb2;
          }
          thr = bk[KK - 1];
        }
      }
    }
    float r0 = thr;
#pragma unroll
    for (int d = 1; d < 16; d <<= 1) r0 = fminf(r0, __shfl_xor(r0, d, 64));
    rowThr = r0;
  }

  unsigned long long* o = part + ((size_t)(i0 + tg) * 2 + jh) * KK;
#pragma unroll
  for (int s = 0; s < KK; ++s) {
    float w = bk[0];
#pragma unroll
    for (int d = 1; d < 16; d <<= 1) w = fminf(w, __shfl_xor(w, d, 64));
    int cj = (bk[0] == w) ? bj[0] : 0x7FFFFFFF;
#pragma unroll
    for (int d = 1; d < 16; d <<= 1) {
      const int oc = __shfl_xor(cj, d, 64);
      cj = (oc < cj) ? oc : cj;
    }
    const bool pop = (bk[0] == w) && (bj[0] == cj);
#pragma unroll
    for (int q = 0; q < KK - 1; ++q) {
      bk[q] = pop ? bk[q + 1] : bk[q];
      bj[q] = pop ? bj[q + 1] : bj[q];
    }
    if (pop) bk[KK - 1] = FINF;
    if (tc == 0)
      o[s] = ((unsigned long long)fkey(w) << 32) | (unsigned)cj;
  }
}

// final merge of the two j-half partials (20 entries) -> idx
__global__ void knn_merge2_kernel(const unsigned long long* __restrict__ part,
                                  int* __restrict__ idx) {
  const int i = blockIdx.x * blockDim.x + threadIdx.x;
  if (i >= T) return;
  const unsigned long long* p = part + (size_t)i * 2 * KK;
  unsigned long long best[KK];
#pragma unroll
  for (int s = 0; s < KK; ++s) best[s] = ~0ULL;
  for (int q = 0; q < 2 * KK; ++q) {
    const unsigned long long v = p[q];
    if (v < best[KK - 1]) ins10(best, v);
  }
#pragma unroll
  for (int s = 0; s < KK; ++s) idx[i * KK + s] = (int)(best[s] & 0xffffffffu);
}

// node GEMM for D=6 (conv1)
__global__ void nodegemm6_kernel(const float* __restrict__ X,
                                 const float* __restrict__ wp,
                                 const float* __restrict__ bp,
                                 float* __restrict__ hb) {
  const int tid = threadIdx.x;
  const int c = tid & 127;
  const int t = blockIdx.x * 2 + (tid >> 7);
  const float* xr = X + (size_t)t * 6;
  float v = bp[c];
#pragma unroll
  for (int d = 0; d < 6; ++d) v = fmaf(xr[d], wp[d * 128 + c], v);
  hb[(size_t)t * 128 + c] = v;
}

// ---------------------------------------------------------------- stat0
// Per-block BN0 partials (no atomics) -> spart[blk][128].
__global__ __launch_bounds__(256) void stat0_kernel(
    const float* __restrict__ hb, const int* __restrict__ idx,
    float* __restrict__ spart) {
  const int wv = threadIdx.x >> 6, lane = threadIdx.x & 63;
  const int e0 = (blockIdx.x * 4 + wv) * 16;
  float s1 = 0.f, s2 = 0.f;
  for (int q = 0; q < 16; ++q) {
    const int e = e0 + q;
    const int t = e / 10;
    const int jg = idx[e];
    const float v = fmaxf(hb[(size_t)t * 128 + lane] +
                          hb[(size_t)jg * 128 + 64 + lane], 0.f);
    s1 += v; s2 = fmaf(v, v, s2);
  }
  __shared__ float ls[4][64];
  ls[wv][lane] = s1;
  __syncthreads();
  if (wv == 0)
    spart[(size_t)blockIdx.x * 128 + lane] =
        ls[0][lane] + ls[1][lane] + ls[2][lane] + ls[3][lane];
  __syncthreads();
  ls[wv][lane] = s2;
  __syncthreads();
  if (wv == 0)
    spart[(size_t)blockIdx.x * 128 + 64 + lane] =
        ls[0][lane] + ls[1][lane] + ls[2][lane] + ls[3][lane];
}

// ---------------------------------------------------------------- BN fold
__global__ void fold_kernel(const float* __restrict__ stat, float cntInv,
                            const float* __restrict__ g, const float* __restrict__ be,
                            const float* __restrict__ W, const float* __restrict__ bias,
                            float* __restrict__ Wf, float* __restrict__ bf,
                            int Cin, int Cout) {
  const int gid = blockIdx.x * blockDim.x + threadIdx.x;
  const int nW = Cin * Cout;
  if (gid < nW) {
    const int d = gid / Cout;
    const float mean = stat[d] * cntInv;
    const float var = fmaf(-mean, mean, stat[1024 + d] * cntInv);
    const float a = g[d] * rsqrtf(var + BN_EPS);
    Wf[gid] = a * W[gid];
  } else if (gid < nW + Cout) {
    const int j = gid - nW;
    float acc = bias[j];
    for (int d = 0; d < Cin; ++d) {
      const float mean = stat[d] * cntInv;
      const float var = fmaf(-mean, mean, stat[1024 + d] * cntInv);
      const float a = g[d] * rsqrtf(var + BN_EPS);
      const float c = fmaf(-mean, a, be[d]);
      acc = fmaf(c, W[d * Cout + j], acc);
    }
    bf[j] = acc;
  }
}

// ---------------------------------------------------------------- mlp1 (node-aligned)
// Block = 160 edge rows = 16 nodes; per-node max/min in registers; BN1
// partials (no atomics) -> spart[blk][128].
__global__ __launch_bounds__(256) void mlp1n_kernel(
    const float* __restrict__ hb, const int* __restrict__ idx,
    const float* __restrict__ w1f, const float* __restrict__ b1f,
    float* __restrict__ xmax, float* __restrict__ xmin,
    float* __restrict__ spart) {
  __shared__ __align__(16) float As[32 * 164];  // [k][row], 160 + 4 pad
  __shared__ __align__(16) float Bs[32][64];
  __shared__ int ids[160];
  __shared__ float red[16][64];
  const int tid = threadIdx.x;
  const int row0 = blockIdx.x * 160;
  const int tn = tid >> 4, tx = tid & 15;
  if (tid < 160) ids[tid] = idx[row0 + tid];
  float acc[10][4] = {};
  for (int kb = 0; kb < 64; kb += 32) {
    __syncthreads();
    for (int f = tid; f < 160 * 8; f += 256) {
      const int r = f >> 3, q = f & 7;
      const int t = blockIdx.x * 16 + r / 10;
      const int jg = ids[r];
      const float4 va = *(const float4*)&hb[(size_t)t * 128 + kb + q * 4];
      const float4 vb = *(const float4*)&hb[(size_t)jg * 128 + 64 + kb + q * 4];
      As[(q * 4 + 0) * 164 + r] = fmaxf(va.x + vb.x, 0.f);
      As[(q * 4 + 1) * 164 + r] = fmaxf(va.y + vb.y, 0.f);
      As[(q * 4 + 2) * 164 + r] = fmaxf(va.z + vb.z, 0.f);
      As[(q * 4 + 3) * 164 + r] = fmaxf(va.w + vb.w, 0.f);
    }
    {
      const int kr = tid >> 4, c4 = tid & 15;
#pragma unroll
      for (int h = 0; h < 2; ++h) {
        const int k2 = kr + h * 16;
        *(float4*)&Bs[k2][c4 * 4] =
            *(const float4*)&w1f[(size_t)(kb + k2) * 64 + c4 * 4];
      }
    }
    __syncthreads();
#pragma unroll
    for (int k = 0; k < 32; ++k) {
      const float* ap = &As[k * 164 + tn * 10];
      const float4 bv = *(const float4*)&Bs[k][tx * 4];
#pragma unroll
      for (int i = 0; i < 10; ++i) {
        const float a = ap[i];
        acc[i][0] = fmaf(a, bv.x, acc[i][0]);
        acc[i][1] = fmaf(a, bv.y, acc[i][1]);
        acc[i][2] = fmaf(a, bv.z, acc[i][2]);
        acc[i][3] = fmaf(a, bv.w, acc[i][3]);
      }
    }
  }
  const int node = blockIdx.x * 16 + tn;
  float s2v[4];
#pragma unroll
  for (int j = 0; j < 4; ++j) {
    const float bj = b1f[tx * 4 + j];
    float mx = -3.4e38f, mn = 3.4e38f, s1 = 0.f, s2 = 0.f;
#pragma unroll
    for (int i = 0; i < 10; ++i) {
      const float v = fmaxf(acc[i][j] + bj, 0.f);
      mx = fmaxf(mx, v); mn = fminf(mn, v);
      s1 += v; s2 = fmaf(v, v, s2);
    }
    xmax[(size_t)node * 64 + tx * 4 + j] = mx;
    xmin[(size_t)node * 64 + tx * 4 + j] = mn;
    red[tn][tx * 4 + j] = s1;
    s2v[j] = s2;
  }
  __syncthreads();
  if (tid < 64) {
    float s = 0.f;
#pragma unroll
    for (int q = 0; q < 16; ++q) s += red[q][tid];
    spart[(size_t)blockIdx.x * 128 + tid] = s;
  }
  __syncthreads();
#pragma unroll
  for (int j = 0; j < 4; ++j) red[tn][tx * 4 + j] = s2v[j];
  __syncthreads();
  if (tid < 64) {
    float s = 0.f;
#pragma unroll
    for (int q = 0; q < 16; ++q) s += red[q][tid];
    spart[(size_t)blockIdx.x * 128 + 64 + tid] = s;
  }
}

// ---------------------------------------------------------------- conv output
__global__ void conv_out_kernel(const float* __restrict__ xmax, const float* __restrict__ xmin,
                                const float* __restrict__ stat, float cntInv,
                                const float* __restrict__ g, const float* __restrict__ be,
                                float* __restrict__ cat, int coff) {
  const int gid = blockIdx.x * blockDim.x + threadIdx.x;
  const int c = gid & 63, t = gid >> 6;
  const float mean = stat[c] * cntInv;
  const float var = fmaf(-mean, mean, stat[1024 + c] * cntInv);
  const float a = g[c] * rsqrtf(var + BN_EPS);
  const float cc = fmaf(-mean, a, be[c]);
  const float v = (a >= 0.f) ? fmaf(a, xmax[gid], cc) : fmaf(a, xmin[gid], cc);
  cat[(size_t)t * 192 + coff + c] = v;
}

// ---------------------------------------------------------------- generic GEMM
// Stats: per-block partials (no atomics) -> spart[blockIdx][128] if spart.
// cmax/cmin: uint atomicMax/Min (exactly associative -> deterministic).
__global__ __launch_bounds__(256) void gemm_kernel(
    const float* __restrict__ A, int lda,
    const float* __restrict__ Bw, int ldb,
    const float* __restrict__ bias, int biasPerGraph,
    float* __restrict__ C,
    float* __restrict__ spart,
    unsigned* __restrict__ cmax, unsigned* __restrict__ cmin,
    int Kdim, int Ncols, int doRelu) {
  __shared__ float As[32][68];
  __shared__ float Bs[32][64];
  const int tid = threadIdx.x;
  const int nbx = Ncols >> 6;
  const int bx = blockIdx.x % nbx, by = blockIdx.x / nbx;
  const int row0 = by << 6, col0 = bx << 6;
  const int tx = tid & 15, ty = tid >> 4;
  float acc[4][4] = {};
  for (int kb = 0; kb < Kdim; kb += 32) {
    __syncthreads();
    {
      const int r = tid >> 3, fc = tid & 7;
#pragma unroll
      for (int h = 0; h < 2; ++h) {
        const int rr = r + h * 32;
        const float4 va = *(const float4*)&A[(size_t)(row0 + rr) * lda + kb + fc * 4];
        As[fc * 4 + 0][rr] = va.x; As[fc * 4 + 1][rr] = va.y;
        As[fc * 4 + 2][rr] = va.z; As[fc * 4 + 3][rr] = va.w;
      }
      const int kr = tid >> 4, c4 = tid & 15;
#pragma unroll
      for (int h = 0; h < 2; ++h) {
        const int k2 = kr + h * 16;
        *(float4*)&Bs[k2][c4 * 4] =
            *(const float4*)&Bw[(size_t)(kb + k2) * ldb + col0 + c4 * 4];
      }
    }
    __syncthreads();
#pragma unroll
    for (int k = 0; k < 32; ++k) {
      const float4 av = *(const float4*)&As[k][ty * 4];
      const float4 bv = *(const float4*)&Bs[k][tx * 4];
      const float a4[4] = {av.x, av.y, av.z, av.w};
      const float b4[4] = {bv.x, bv.y, bv.z, bv.w};
#pragma unroll
      for (int i = 0; i < 4; ++i)
#pragma unroll
        for (int j = 0; j < 4; ++j) acc[i][j] = fmaf(a4[i], b4[j], acc[i][j]);
    }
  }
  const int graph = row0 >> 11;
  const float* bp = bias + (biasPerGraph ? graph * Ncols : 0) + col0 + tx * 4;
  float v[4][4];
#pragma unroll
  for (int j = 0; j < 4; ++j) {
    const float bj = bp[j];
#pragma unroll
    for (int i = 0; i < 4; ++i) {
      const float s = acc[i][j] + bj;
      v[i][j] = doRelu ? fmaxf(s, 0.f) : s;
    }
  }
  if (C) {
#pragma unroll
    for (int i = 0; i < 4; ++i) {
      const float4 st = make_float4(v[i][0], v[i][1], v[i][2], v[i][3]);
      *(float4*)&C[(size_t)(row0 + ty * 4 + i) * Ncols + col0 + tx * 4] = st;
    }
  }
  if (spart) {
    __syncthreads();
#pragma unroll
    for (int j = 0; j < 4; ++j)
      As[ty][tx * 4 + j] = v[0][j] + v[1][j] + v[2][j] + v[3][j];
    __syncthreads();
    if (tid < 64) {
      float s = 0.f;
#pragma unroll
      for (int q = 0; q < 16; ++q) s += As[q][tid];
      spart[(size_t)blockIdx.x * 128 + tid] = s;
    }
    __syncthreads();
#pragma unroll
    for (int j = 0; j < 4; ++j) {
      float s = 0.f;
#pragma unroll
      for (int i = 0; i < 4; ++i) s = fmaf(v[i][j], v[i][j], s);
      As[ty][tx * 4 + j] = s;
    }
    __syncthreads();
    if (tid < 64) {
      float s = 0.f;
#pragma unroll
      for (int q = 0; q < 16; ++q) s += As[q][tid];
      spart[(size_t)blockIdx.x * 128 + 64 + tid] = s;
    }
    if (cmax) {
      __syncthreads();
#pragma unroll
      for (int j = 0; j < 4; ++j)
        As[ty][tx * 4 + j] = fmaxf(fmaxf(v[0][j], v[1][j]), fmaxf(v[2][j], v[3][j]));
      __syncthreads();
      if (tid < 64) {
        float s = As[0][tid];
#pragma unroll
        for (int q = 1; q < 16; ++q) s = fmaxf(s, As[q][tid]);
        atomicMax(&cmax[graph * Ncols + col0 + tid], fkey(s));
      }
      __syncthreads();
#pragma unroll
      for (int j = 0; j < 4; ++j)
        As[ty][tx * 4 + j] = fminf(fminf(v[0][j], v[1][j]), fminf(v[2][j], v[3][j]));
      __syncthreads();
      if (tid < 64) {
        float s = As[0][tid];
#pragma unroll
        for (int q = 1; q < 16; ++q) s = fminf(s, As[q][tid]);
        atomicMin(&cmin[graph * Ncols + col0 + tid], fkey(s));
      }
    }
  }
}

// ---------------------------------------------------------------- pooled (normalized)
__global__ void pool_finalize_kernel(const unsigned* __restrict__ cmax,
                                     const unsigned* __restrict__ cmin,
                                     const float* __restrict__ stat, float cntInv,
                                     const float* __restrict__ g, const float* __restrict__ be,
                                     float* __restrict__ pooled) {
  const int gid = blockIdx.x * blockDim.x + threadIdx.x;
  if (gid >= NBG * 1024) return;
  const int col = gid & 1023;
  const float mean = stat[col] * cntInv;
  const float var = fmaf(-mean, mean, stat[1024 + col] * cntInv);
  const float a = g[col] * rsqrtf(var + BN_EPS);
  const float cc = fmaf(-mean, a, be[col]);
  const float fx = funkey(cmax[gid]), fn = funkey(cmin[gid]);
  pooled[gid] = (a >= 0.f) ? fmaf(a, fx, cc) : fmaf(a, fn, cc);
}

// po[b][j] = m0_b[j] + pooled[b] @ m0_w[192:1216]
__global__ void po_gemm_kernel(const float* __restrict__ pooled,
                               const float* __restrict__ w2,
                               const float* __restrict__ m0b,
                               float* __restrict__ po) {
  const int b = blockIdx.x, j = threadIdx.x;
  const float* pr = pooled + b * 1024;
  float a0 = m0b[j], a1 = 0.f, a2 = 0.f, a3 = 0.f;
  for (int d = 0; d < 1024; d += 4) {
    a0 = fmaf(pr[d + 0], w2[(size_t)(d + 0) * 256 + j], a0);
    a1 = fmaf(pr[d + 1], w2[(size_t)(d + 1) * 256 + j], a1);
    a2 = fmaf(pr[d + 2], w2[(size_t)(d + 2) * 256 + j], a2);
    a3 = fmaf(pr[d + 3], w2[(size_t)(d + 3) * 256 + j], a3);
  }
  po[b * 256 + j] = (a0 + a1) + (a2 + a3);
}

// out[t] = hm1[t] @ m2f + b2f
__global__ __launch_bounds__(256) void m2_gemv_kernel(
    const float* __restrict__ hm1, const float* __restrict__ m2f,
    const float* __restrict__ m2fb, float* __restrict__ out) {
  const int wv = threadIdx.x >> 6, lane = threadIdx.x & 63;
  const int t = blockIdx.x * 4 + wv;
  const float* r = hm1 + (size_t)t * 128;
  float v = fmaf(r[lane], m2f[lane], r[64 + lane] * m2f[64 + lane]);
  for (int off = 32; off; off >>= 1) v += __shfl_down(v, off);
  if (lane == 0) out[t] = v + m2fb[0];
}

// ---------------------------------------------------------------------------
extern "C" void kernel_launch(void* const* d_in, const int* in_sizes, int n_in,
                              void* d_out, int out_size, void* d_ws, size_t ws_size,
                              hipStream_t stream) {
  const float* x = (const float*)d_in[0];
  const float* c_w0[3] = {(const float*)d_in[1], (const float*)d_in[9],  (const float*)d_in[17]};
  const float* c_b0[3] = {(const float*)d_in[2], (const float*)d_in[10], (const float*)d_in[18]};
  const float* c_g0[3] = {(const float*)d_in[3], (const float*)d_in[11], (const float*)d_in[19]};
  const float* c_be0[3]= {(const float*)d_in[4], (const float*)d_in[12], (const float*)d_in[20]};
  const float* c_w1[3] = {(const float*)d_in[5], (const float*)d_in[13], (const float*)d_in[21]};
  const float* c_b1[3] = {(const float*)d_in[6], (const float*)d_in[14], (const float*)d_in[22]};
  const float* c_g1[3] = {(const float*)d_in[7], (const float*)d_in[15], (const float*)d_in[23]};
  const float* c_be1[3]= {(const float*)d_in[8], (const float*)d_in[16], (const float*)d_in[24]};
  const float* l1_w = (const float*)d_in[25];
  const float* l1_b = (const float*)d_in[26];
  const float* l1_g = (const float*)d_in[27];
  const float* l1_be= (const float*)d_in[28];
  const float* m0_w = (const float*)d_in[29];
  const float* m0_b = (const float*)d_in[30];
  const float* m0_g = (const float*)d_in[31];
  const float* m0_be= (const float*)d_in[32];
  const float* m1_w = (const float*)d_in[33];
  const float* m1_b = (const float*)d_in[34];
  const float* m1_g = (const float*)d_in[35];
  const float* m1_be= (const float*)d_in[36];
  const float* m2_w = (const float*)d_in[37];
  const float* m2_b = (const float*)d_in[38];
  float* out = (float*)d_out;

  char* ws = (char*)d_ws;
  float*    stats  = (float*)(ws + 0);
  unsigned* cmax   = (unsigned*)(ws + 73728);
  unsigned* cmin   = (unsigned*)(ws + 106496);
  float*    pooled = (float*)(ws + 139264);
  float*    po     = (float*)(ws + 172032);
  float*    w1f    = (float*)(ws + 180224);
  float*    b1f    = (float*)(ws + 196608);
  float*    m1f    = (float*)(ws + 196864);
  float*    m1fb   = (float*)(ws + 327936);
  float*    m2f    = (float*)(ws + 328448);
  float*    m2fb   = (float*)(ws + 328960);
  int*      idx    = (int*)  (ws + 394752);     // [T][10]
  float*    xmax   = (float*)(ws + 1050112);    // [T][64]
  float*    xmin   = (float*)(ws + 5244416);    // [T][64]
  float*    cat    = (float*)(ws + 9438720);    // [T][192]
  float*    wp[3]  = {(float*)(ws + 22021632),
                      (float*)(ws + 22025216),
                      (float*)(ws + 22058496)};
  float*    bp[3]  = {(float*)(ws + 22024704), (float*)(ws + 22057984),
                      (float*)(ws + 22091264)};
  char*     regA   = ws + 22091776;
  unsigned long long* part = (unsigned long long*)regA;   // [T][2][10]
  float*    hb     = (float*)(regA + 2621440);  // [T][128] (conv phase)
  float*    hm0    = (float*)regA;              // [T][256] (post-conv)
  float*    hm1    = (float*)(regA + 16777216); // [T][128] (post-conv)
  float*    spart  = (float*)(ws + 47257600);   // [<=4096][128] stat partials

  const float cInvE = 1.f / (float)(T * KK);
  const float cInvT = 1.f / (float)T;

  prep_kernel<<<142, 256, 0, stream>>>(stats, cmax, cmin,
                                       c_w0[0], c_b0[0], c_w0[1], c_b0[1], c_w0[2], c_b0[2],
                                       wp[0], bp[0], wp[1], bp[1], wp[2], bp[2]);

  for (int cidx = 0; cidx < 3; ++cidx) {
    const float* Xin; int ldx, Din;
    const int coff = cidx * 64;
    if (cidx == 0) { Xin = x; ldx = 6; Din = 6; }
    else { Xin = cat + (cidx - 1) * 64; ldx = 192; Din = 64; }
    float* st0 = stats + (cidx * 2) * 2048;
    float* st1 = stats + (cidx * 2 + 1) * 2048;

    if (Din == 6)
      knn6_kernel<<<2048, 256, 0, stream>>>(Xin, part);
    else
      knn64_kernel<<<1024, 256, 0, stream>>>(Xin, ldx, part);
    knn_merge2_kernel<<<T / 256, 256, 0, stream>>>(part, idx);
    if (Din == 6)
      nodegemm6_kernel<<<T / 2, 256, 0, stream>>>(Xin, wp[0], bp[0], hb);
    else
      gemm_kernel<<<(T / 64) * 2, 256, 0, stream>>>(
          Xin, ldx, wp[cidx], 128, bp[cidx], 0, hb,
          nullptr, nullptr, nullptr, 64, 128, 0);
    stat0_kernel<<<T * KK / 64, 256, 0, stream>>>(hb, idx, spart);
    statredN_kernel<<<1, 128, 0, stream>>>(spart, T * KK / 64, 1, st0);
    fold_kernel<<<17, 256, 0, stream>>>(st0, cInvE, c_g0[cidx], c_be0[cidx],
                                        c_w1[cidx], c_b1[cidx], w1f, b1f, 64, 64);
    mlp1n_kernel<<<T * KK / 160, 256, 0, stream>>>(hb, idx, w1f, b1f,
                                                   xmax, xmin, spart);
    statredN_kernel<<<1, 128, 0, stream>>>(spart, T * KK / 160, 1, st1);
    conv_out_kernel<<<T * 64 / 256, 256, 0, stream>>>(xmax, xmin, st1, cInvE,
                                                      c_g1[cidx], c_be1[cidx], cat, coff);
  }

  float* stl1 = stats + 6 * 2048;
  gemm_kernel<<<(T / 64) * (1024 / 64), 256, 0, stream>>>(
      cat, 192, l1_w, 1024, l1_b, 0, nullptr, spart, cmax, cmin, 192, 1024, 1);
  statredN_kernel<<<16, 128, 0, stream>>>(spart, T / 64, 16, stl1);
  pool_finalize_kernel<<<32, 256, 0, stream>>>(cmax, cmin, stl1, cInvT, l1_g, l1_be, pooled);
  po_gemm_kernel<<<8, 256, 0, stream>>>(pooled, m0_w + 192 * 256, m0_b, po);

  float* stm0 = stats + 7 * 2048;
  gemm_kernel<<<(T / 64) * (256 / 64), 256, 0, stream>>>(
      cat, 192, m0_w, 256, po, 1, hm0, spart, nullptr, nullptr, 192, 256, 1);
  statredN_kernel<<<4, 128, 0, stream>>>(spart, T / 64, 4, stm0);
  fold_kernel<<<129, 256, 0, stream>>>(stm0, cInvT, m0_g, m0_be, m1_w, m1_b, m1f, m1fb, 256, 128);

  float* stm1 = stats + 8 * 2048;
  gemm_kernel<<<(T / 64) * (128 / 64), 256, 0, stream>>>(
      hm0, 256, m1f, 128, m1fb, 0, hm1, spart, nullptr, nullptr, 256, 128, 1);
  statredN_kernel<<<2, 128, 0, stream>>>(spart, T / 64, 2, stm1);
  fold_kernel<<<1, 256, 0, stream>>>(stm1, cInvT, m1_g, m1_be, m2_w, m2_b, m2f, m2fb, 128, 1);
  m2_gemv_kernel<<<T / 4, 256, 0, stream>>>(hm1, m2f, m2fb, out);
}

// Round 15
// 1225.137 us; speedup vs baseline: 1.6454x; 1.5519x over previous
//
#include <hip/hip_runtime.h>
#include <stdint.h>

// ---------------------------------------------------------------------------
// DGCNN forward on MI355X. All fp32. B=8 graphs x N=2048 nodes, D0=6, K=10.
// BN folded into following layer weights; max-pools on raw activations via
// monotone-affine trick; x5 branch of m0 reduced to [8,1024]@[1024,256].
// R14: stat reduction parallelized — R13's single-block statredN read 2560
// cross-XCD partials through one CU (~500cyc/line, ~540us total). Now
// two-level: statred1 (64 parallel blocks, fixed slices) -> spart2[64][128],
// then statredN over 64 rows. Both levels fixed-order -> deterministic.
// ---------------------------------------------------------------------------

constexpr int T  = 16384;   // total nodes
constexpr int NBG = 8;      // graphs
constexpr int NN = 2048;    // nodes per graph
constexpr int KK = 10;      // kNN
constexpr float BN_EPS = 1e-5f;

__device__ __forceinline__ unsigned fkey(float f) {
  unsigned u = __float_as_uint(f);
  return (u & 0x80000000u) ? ~u : (u | 0x80000000u);
}
__device__ __forceinline__ float funkey(unsigned k) {
  unsigned u = (k & 0x80000000u) ? (k ^ 0x80000000u) : ~k;
  return __uint_as_float(u);
}

__device__ __forceinline__ void ins10(unsigned long long (&b)[KK],
                                      unsigned long long v) {
  b[KK - 1] = v;
#pragma unroll
  for (int s = KK - 1; s > 0; --s)
    if (b[s] < b[s - 1]) {
      unsigned long long t2 = b[s]; b[s] = b[s - 1]; b[s - 1] = t2;
    }
}

// ---------------------------------------------------------------- prep
__global__ void prep_kernel(float* __restrict__ stats,
                            unsigned* __restrict__ cmax, unsigned* __restrict__ cmin,
                            const float* __restrict__ w0a, const float* __restrict__ b0a,
                            const float* __restrict__ w0b, const float* __restrict__ b0b,
                            const float* __restrict__ w0c, const float* __restrict__ b0c,
                            float* __restrict__ wpa, float* __restrict__ bpa,
                            float* __restrict__ wpb, float* __restrict__ bpb,
                            float* __restrict__ wpc, float* __restrict__ bpc) {
  const int blk = blockIdx.x, tid = threadIdx.x;
  if (blk < 72) {
    const int gid = blk * 256 + tid;
    if (gid < 9 * 2048) stats[gid] = 0.f;
    if (gid < NBG * 1024) { cmax[gid] = 0u; cmin[gid] = 0xFFFFFFFFu; }
    return;
  }
  const float* w0; const float* b0; float* wp; float* bp; int D, gid;
  if (blk < 76)       { w0 = w0a; b0 = b0a; wp = wpa; bp = bpa; D = 6;  gid = (blk - 72) * 256 + tid; }
  else if (blk < 109) { w0 = w0b; b0 = b0b; wp = wpb; bp = bpb; D = 64; gid = (blk - 76) * 256 + tid; }
  else                { w0 = w0c; b0 = b0c; wp = wpc; bp = bpc; D = 64; gid = (blk - 109) * 256 + tid; }
  if (gid < D * 128) {
    const int d = gid >> 7, c = gid & 127;
    wp[gid] = (c < 64) ? (w0[d * 64 + c] - w0[(D + d) * 64 + c])
                       : w0[(D + d) * 64 + (c - 64)];
  } else if (gid < D * 128 + 128) {
    const int c = gid - D * 128;
    bp[c] = (c < 64) ? b0[c] : 0.f;
  }
}

// ---------------------------------------------------------------- stat reduce
// Level 1: block ch reduces contiguous rows [ch*per, min(+per, nby)) of
// part[row][128] in fixed order -> out2[ch][128]. Deterministic.
__global__ void statred1_kernel(const float* __restrict__ part, int nby, int per,
                                float* __restrict__ out2) {
  const int t = threadIdx.x;      // 128
  const int ch = blockIdx.x;
  const int y0 = ch * per;
  const int y1 = (y0 + per < nby) ? (y0 + per) : nby;
  float s0 = 0.f, s1 = 0.f, s2 = 0.f, s3 = 0.f;
  int by = y0;
  for (; by + 4 <= y1; by += 4) {
    s0 += part[(size_t)(by + 0) * 128 + t];
    s1 += part[(size_t)(by + 1) * 128 + t];
    s2 += part[(size_t)(by + 2) * 128 + t];
    s3 += part[(size_t)(by + 3) * 128 + t];
  }
  for (; by < y1; ++by) s0 += part[(size_t)by * 128 + t];
  out2[(size_t)ch * 128 + t] = (s0 + s1) + (s2 + s3);
}

// Level 2 / generic: fixed-order reduce over nby rows (stride nbx, column bx)
// -> stat[bx*64 + c] / stat[1024 + bx*64 + c].
__global__ void statredN_kernel(const float* __restrict__ part, int nby, int nbx,
                                float* __restrict__ stat) {
  const int t = threadIdx.x;      // 128
  const int bx = blockIdx.x;
  float s0 = 0.f, s1 = 0.f, s2 = 0.f, s3 = 0.f;
  int by = 0;
  for (; by + 4 <= nby; by += 4) {
    s0 += part[(size_t)((by + 0) * nbx + bx) * 128 + t];
    s1 += part[(size_t)((by + 1) * nbx + bx) * 128 + t];
    s2 += part[(size_t)((by + 2) * nbx + bx) * 128 + t];
    s3 += part[(size_t)((by + 3) * nbx + bx) * 128 + t];
  }
  for (; by < nby; ++by) s0 += part[(size_t)(by * nbx + bx) * 128 + t];
  const float s = (s0 + s1) + (s2 + s3);
  if (t < 64) stat[bx * 64 + t] = s;
  else        stat[1024 + bx * 64 + (t - 64)] = s;
}

// ---------------------------------------------------------------- kNN D=64
// Block = 32 rows x 1024 j (jh=blk&1). 16 groups x 16 lanes; group owns rows
// {2tg,2tg+1}, lane owns cols [tc*32,+32). Bs [k][g32][36] (144B stride,
// 16B-aligned, conflict-free). sq inline from staged B. Stable strict-<
// insert + exact row-reject threshold + tournament merge -> part[T][2][10].
__global__ __launch_bounds__(256) void knn64_kernel(
    const float* __restrict__ X, int ldx,
    unsigned long long* __restrict__ part /* [T][2][10] */) {
  constexpr int AF = 64 * 32;
  constexpr int BF = 8 * 576;
  __shared__ __align__(16) float smem[AF + BF + 576];
  float* As = smem;
  float* Bs = smem + AF;
  float* sqs = smem + AF + BF;

  const int tid = threadIdx.x;
  const int blk = blockIdx.x;
  const int b = blk >> 7;
  const int rem = blk & 127;
  const int ib = rem >> 1, jh = rem & 1;
  const int i0 = b * NN + ib * 32;
  const int jg0 = b * NN + jh * 1024;
  const int tg = tid >> 4, tc = tid & 15;

  {
    const int r = tid & 31, ks = (tid >> 5) * 8;
    const float* rp = &X[(size_t)(i0 + r) * ldx + ks];
    const float4 v0 = *(const float4*)rp;
    const float4 v1 = *(const float4*)(rp + 4);
    As[(ks + 0) * 32 + r] = v0.x; As[(ks + 1) * 32 + r] = v0.y;
    As[(ks + 2) * 32 + r] = v0.z; As[(ks + 3) * 32 + r] = v0.w;
    As[(ks + 4) * 32 + r] = v1.x; As[(ks + 5) * 32 + r] = v1.y;
    As[(ks + 6) * 32 + r] = v1.z; As[(ks + 7) * 32 + r] = v1.w;
  }

  const float FINF = __int_as_float(0x7F800000);
  float bk0[KK], bk1[KK]; int bj0[KK], bj1[KK];
#pragma unroll
  for (int s = 0; s < KK; ++s) { bk0[s] = FINF; bj0[s] = 0; bk1[s] = FINF; bj1[s] = 0; }
  float thr0 = FINF, thr1 = FINF, rowThr0 = FINF, rowThr1 = FINF;

  for (int jt = 0; jt < 2; ++jt) {
    const int jtbase = jg0 + jt * 512;
    float acc0[32] = {}, acc1[32] = {};
    float sqa0 = 0.f, sqa1 = 0.f;

    for (int kb = 0; kb < 64; kb += 8) {
      __syncthreads();
#pragma unroll
      for (int h = 0; h < 2; ++h) {
        const int c = tid + h * 256;
        const float* rp = &X[(size_t)(jtbase + c) * ldx + kb];
        const float4 v0 = *(const float4*)rp;
        const float4 v1 = *(const float4*)(rp + 4);
        const int co = (c >> 5) * 36 + (c & 31);
        Bs[0 * 576 + co] = v0.x; Bs[1 * 576 + co] = v0.y;
        Bs[2 * 576 + co] = v0.z; Bs[3 * 576 + co] = v0.w;
        Bs[4 * 576 + co] = v1.x; Bs[5 * 576 + co] = v1.y;
        Bs[6 * 576 + co] = v1.z; Bs[7 * 576 + co] = v1.w;
        float sq = v0.x * v0.x;
        sq = fmaf(v0.y, v0.y, sq); sq = fmaf(v0.z, v0.z, sq);
        sq = fmaf(v0.w, v0.w, sq); sq = fmaf(v1.x, v1.x, sq);
        sq = fmaf(v1.y, v1.y, sq); sq = fmaf(v1.z, v1.z, sq);
        sq = fmaf(v1.w, v1.w, sq);
        if (h == 0) sqa0 += sq; else sqa1 += sq;
        if (kb == 56) sqs[co] = (h == 0) ? sqa0 : sqa1;
      }
      __syncthreads();
#pragma unroll
      for (int kk = 0; kk < 8; ++kk) {
        const float2 av = *(const float2*)&As[(kb + kk) * 32 + 2 * tg];
        const float a0 = av.x, a1 = av.y;
        const float* bp = &Bs[kk * 576 + tc * 36];
#pragma unroll
        for (int c4 = 0; c4 < 8; ++c4) {
          const float4 bv = *(const float4*)(bp + c4 * 4);
          acc0[c4 * 4 + 0] = fmaf(a0, bv.x, acc0[c4 * 4 + 0]);
          acc0[c4 * 4 + 1] = fmaf(a0, bv.y, acc0[c4 * 4 + 1]);
          acc0[c4 * 4 + 2] = fmaf(a0, bv.z, acc0[c4 * 4 + 2]);
          acc0[c4 * 4 + 3] = fmaf(a0, bv.w, acc0[c4 * 4 + 3]);
          acc1[c4 * 4 + 0] = fmaf(a1, bv.x, acc1[c4 * 4 + 0]);
          acc1[c4 * 4 + 1] = fmaf(a1, bv.y, acc1[c4 * 4 + 1]);
          acc1[c4 * 4 + 2] = fmaf(a1, bv.z, acc1[c4 * 4 + 2]);
          acc1[c4 * 4 + 3] = fmaf(a1, bv.w, acc1[c4 * 4 + 3]);
        }
      }
    }

    // selection (stable strict-< insert; exact; R8 argument)
#pragma unroll
    for (int c4 = 0; c4 < 8; ++c4) {
      const float4 sv = *(const float4*)&sqs[tc * 36 + c4 * 4];
      const float svv[4] = {sv.x, sv.y, sv.z, sv.w};
#pragma unroll
      for (int u = 0; u < 4; ++u) {
        const int c = c4 * 4 + u;
        const int j = jtbase + tc * 32 + c;
        const float m0 = fmaf(-2.f, acc0[c], svv[u]);
        if (m0 <= rowThr0 && m0 < thr0) {
          bk0[KK - 1] = m0; bj0[KK - 1] = j;
#pragma unroll
          for (int s = KK - 1; s > 0; --s) {
            const bool sw = bk0[s] < bk0[s - 1];
            const float ka = bk0[s - 1], kb2 = bk0[s];
            bk0[s - 1] = sw ? kb2 : ka; bk0[s] = sw ? ka : kb2;
            const int ja = bj0[s - 1], jb2 = bj0[s];
            bj0[s - 1] = sw ? jb2 : ja; bj0[s] = sw ? ja : jb2;
          }
          thr0 = bk0[KK - 1];
        }
        const float m1 = fmaf(-2.f, acc1[c], svv[u]);
        if (m1 <= rowThr1 && m1 < thr1) {
          bk1[KK - 1] = m1; bj1[KK - 1] = j;
#pragma unroll
          for (int s = KK - 1; s > 0; --s) {
            const bool sw = bk1[s] < bk1[s - 1];
            const float ka = bk1[s - 1], kb2 = bk1[s];
            bk1[s - 1] = sw ? kb2 : ka; bk1[s] = sw ? ka : kb2;
            const int ja = bj1[s - 1], jb2 = bj1[s];
            bj1[s - 1] = sw ? jb2 : ja; bj1[s] = sw ? ja : jb2;
          }
          thr1 = bk1[KK - 1];
        }
      }
    }
    float r0 = thr0, r1 = thr1;
#pragma unroll
    for (int d = 1; d < 16; d <<= 1) {
      r0 = fminf(r0, __shfl_xor(r0, d, 64));
      r1 = fminf(r1, __shfl_xor(r1, d, 64));
    }
    rowThr0 = r0; rowThr1 = r1;
  }

  // tournament merge: 10 rounds per row over the 16 tc lanes
#pragma unroll
  for (int s = 0; s < KK; ++s) {
    float w0 = bk0[0];
#pragma unroll
    for (int d = 1; d < 16; d <<= 1) w0 = fminf(w0, __shfl_xor(w0, d, 64));
    int cj0 = (bk0[0] == w0) ? bj0[0] : 0x7FFFFFFF;
#pragma unroll
    for (int d = 1; d < 16; d <<= 1) {
      const int oc = __shfl_xor(cj0, d, 64);
      cj0 = (oc < cj0) ? oc : cj0;
    }
    const bool pop0 = (bk0[0] == w0) && (bj0[0] == cj0);
#pragma unroll
    for (int q = 0; q < KK - 1; ++q) {
      bk0[q] = pop0 ? bk0[q + 1] : bk0[q];
      bj0[q] = pop0 ? bj0[q + 1] : bj0[q];
    }
    if (pop0) bk0[KK - 1] = FINF;
    if (tc == 0)
      part[((size_t)(i0 + 2 * tg) * 2 + jh) * KK + s] =
          ((unsigned long long)fkey(w0) << 32) | (unsigned)cj0;

    float w1 = bk1[0];
#pragma unroll
    for (int d = 1; d < 16; d <<= 1) w1 = fminf(w1, __shfl_xor(w1, d, 64));
    int cj1 = (bk1[0] == w1) ? bj1[0] : 0x7FFFFFFF;
#pragma unroll
    for (int d = 1; d < 16; d <<= 1) {
      const int oc = __shfl_xor(cj1, d, 64);
      cj1 = (oc < cj1) ? oc : cj1;
    }
    const bool pop1 = (bk1[0] == w1) && (bj1[0] == cj1);
#pragma unroll
    for (int q = 0; q < KK - 1; ++q) {
      bk1[q] = pop1 ? bk1[q + 1] : bk1[q];
      bj1[q] = pop1 ? bj1[q + 1] : bj1[q];
    }
    if (pop1) bk1[KK - 1] = FINF;
    if (tc == 1)
      part[((size_t)(i0 + 2 * tg + 1) * 2 + jh) * KK + s] =
          ((unsigned long long)fkey(w1) << 32) | (unsigned)cj1;
  }
}

// ---------------------------------------------------------------- kNN D=6
__global__ __launch_bounds__(256) void knn6_kernel(
    const float* __restrict__ X,
    unsigned long long* __restrict__ part /* [T][2][10] */) {
  constexpr int AF = 6 * 16;
  constexpr int BF = 6 * 576;
  __shared__ __align__(16) float smem[AF + BF + 576];
  float* As = smem;
  float* Bs = smem + AF;
  float* sqs = smem + AF + BF;

  const int tid = threadIdx.x;
  const int blk = blockIdx.x;
  const int b = blk >> 8;
  const int rem = blk & 255;
  const int ib = rem >> 1, jh = rem & 1;
  const int i0 = b * NN + ib * 16;
  const int jg0 = b * NN + jh * 1024;
  const int tg = tid >> 4, tc = tid & 15;

  {
    const int r = tid & 15, k = tid >> 4;
    if (k < 6) As[k * 16 + r] = X[(size_t)(i0 + r) * 6 + k];
  }

  const float FINF = __int_as_float(0x7F800000);
  float bk[KK]; int bj[KK];
#pragma unroll
  for (int s = 0; s < KK; ++s) { bk[s] = FINF; bj[s] = 0; }
  float thr = FINF, rowThr = FINF;

  for (int jt = 0; jt < 2; ++jt) {
    const int jtbase = jg0 + jt * 512;
    float acc[32] = {};
    __syncthreads();
#pragma unroll
    for (int h = 0; h < 2; ++h) {
      const int c = tid + h * 256;
      const float* rp = &X[(size_t)(jtbase + c) * 6];
      const int co = (c >> 5) * 36 + (c & 31);
      float sq = 0.f;
#pragma unroll
      for (int k = 0; k < 6; ++k) {
        const float v = rp[k];
        Bs[k * 576 + co] = v;
        sq = fmaf(v, v, sq);
      }
      sqs[co] = sq;
    }
    __syncthreads();
#pragma unroll
    for (int kk = 0; kk < 6; ++kk) {
      const float a0 = As[kk * 16 + tg];
      const float* bp = &Bs[kk * 576 + tc * 36];
#pragma unroll
      for (int c4 = 0; c4 < 8; ++c4) {
        const float4 bv = *(const float4*)(bp + c4 * 4);
        acc[c4 * 4 + 0] = fmaf(a0, bv.x, acc[c4 * 4 + 0]);
        acc[c4 * 4 + 1] = fmaf(a0, bv.y, acc[c4 * 4 + 1]);
        acc[c4 * 4 + 2] = fmaf(a0, bv.z, acc[c4 * 4 + 2]);
        acc[c4 * 4 + 3] = fmaf(a0, bv.w, acc[c4 * 4 + 3]);
      }
    }
#pragma unroll
    for (int c4 = 0; c4 < 8; ++c4) {
      const float4 sv = *(const float4*)&sqs[tc * 36 + c4 * 4];
      const float svv[4] = {sv.x, sv.y, sv.z, sv.w};
#pragma unroll
      for (int u = 0; u < 4; ++u) {
        const int c = c4 * 4 + u;
        const int j = jtbase + tc * 32 + c;
        const float m = fmaf(-2.f, acc[c], svv[u]);
        if (m <= rowThr && m < thr) {
          bk[KK - 1] = m; bj[KK - 1] = j;
#pragma unroll
          for (int s = KK - 1; s > 0; --s) {
            const bool sw = bk[s] < bk[s - 1];
            const float ka = bk[s - 1], kb2 = bk[s];
            bk[s - 1] = sw ? kb2 : ka; bk[s] = sw ? ka : kb2;
            const int ja = bj[s - 1], jb2 = bj[s];
            bj[s - 1] = sw ? jb2 : ja; bj[s] = sw ? ja : jb2;
          }
          thr = bk[KK - 1];
        }
      }
    }
    float r0 = thr;
#pragma unroll
    for (int d = 1; d < 16; d <<= 1) r0 = fminf(r0, __shfl_xor(r0, d, 64));
    rowThr = r0;
  }

  unsigned long long* o = part + ((size_t)(i0 + tg) * 2 + jh) * KK;
#pragma unroll
  for (int s = 0; s < KK; ++s) {
    float w = bk[0];
#pragma unroll
    for (int d = 1; d < 16; d <<= 1) w = fminf(w, __shfl_xor(w, d, 64));
    int cj = (bk[0] == w) ? bj[0] : 0x7FFFFFFF;
#pragma unroll
    for (int d = 1; d < 16; d <<= 1) {
      const int oc = __shfl_xor(cj, d, 64);
      cj = (oc < cj) ? oc : cj;
    }
    const bool pop = (bk[0] == w) && (bj[0] == cj);
#pragma unroll
    for (int q = 0; q < KK - 1; ++q) {
      bk[q] = pop ? bk[q + 1] : bk[q];
      bj[q] = pop ? bj[q + 1] : bj[q];
    }
    if (pop) bk[KK - 1] = FINF;
    if (tc == 0)
      o[s] = ((unsigned long long)fkey(w) << 32) | (unsigned)cj;
  }
}

// final merge of the two j-half partials (20 entries) -> idx
__global__ void knn_merge2_kernel(const unsigned long long* __restrict__ part,
                                  int* __restrict__ idx) {
  const int i = blockIdx.x * blockDim.x + threadIdx.x;
  if (i >= T) return;
  const unsigned long long* p = part + (size_t)i * 2 * KK;
  unsigned long long best[KK];
#pragma unroll
  for (int s = 0; s < KK; ++s) best[s] = ~0ULL;
  for (int q = 0; q < 2 * KK; ++q) {
    const unsigned long long v = p[q];
    if (v < best[KK - 1]) ins10(best, v);
  }
#pragma unroll
  for (int s = 0; s < KK; ++s) idx[i * KK + s] = (int)(best[s] & 0xffffffffu);
}

// node GEMM for D=6 (conv1)
__global__ void nodegemm6_kernel(const float* __restrict__ X,
                                 const float* __restrict__ wp,
                                 const float* __restrict__ bp,
                                 float* __restrict__ hb) {
  const int tid = threadIdx.x;
  const int c = tid & 127;
  const int t = blockIdx.x * 2 + (tid >> 7);
  const float* xr = X + (size_t)t * 6;
  float v = bp[c];
#pragma unroll
  for (int d = 0; d < 6; ++d) v = fmaf(xr[d], wp[d * 128 + c], v);
  hb[(size_t)t * 128 + c] = v;
}

// ---------------------------------------------------------------- stat0
// Per-block BN0 partials (no atomics) -> spart[blk][128].
__global__ __launch_bounds__(256) void stat0_kernel(
    const float* __restrict__ hb, const int* __restrict__ idx,
    float* __restrict__ spart) {
  const int wv = threadIdx.x >> 6, lane = threadIdx.x & 63;
  const int e0 = (blockIdx.x * 4 + wv) * 16;
  float s1 = 0.f, s2 = 0.f;
  for (int q = 0; q < 16; ++q) {
    const int e = e0 + q;
    const int t = e / 10;
    const int jg = idx[e];
    const float v = fmaxf(hb[(size_t)t * 128 + lane] +
                          hb[(size_t)jg * 128 + 64 + lane], 0.f);
    s1 += v; s2 = fmaf(v, v, s2);
  }
  __shared__ float ls[4][64];
  ls[wv][lane] = s1;
  __syncthreads();
  if (wv == 0)
    spart[(size_t)blockIdx.x * 128 + lane] =
        ls[0][lane] + ls[1][lane] + ls[2][lane] + ls[3][lane];
  __syncthreads();
  ls[wv][lane] = s2;
  __syncthreads();
  if (wv == 0)
    spart[(size_t)blockIdx.x * 128 + 64 + lane] =
        ls[0][lane] + ls[1][lane] + ls[2][lane] + ls[3][lane];
}

// ---------------------------------------------------------------- BN fold
__global__ void fold_kernel(const float* __restrict__ stat, float cntInv,
                            const float* __restrict__ g, const float* __restrict__ be,
                            const float* __restrict__ W, const float* __restrict__ bias,
                            float* __restrict__ Wf, float* __restrict__ bf,
                            int Cin, int Cout) {
  const int gid = blockIdx.x * blockDim.x + threadIdx.x;
  const int nW = Cin * Cout;
  if (gid < nW) {
    const int d = gid / Cout;
    const float mean = stat[d] * cntInv;
    const float var = fmaf(-mean, mean, stat[1024 + d] * cntInv);
    const float a = g[d] * rsqrtf(var + BN_EPS);
    Wf[gid] = a * W[gid];
  } else if (gid < nW + Cout) {
    const int j = gid - nW;
    float acc = bias[j];
    for (int d = 0; d < Cin; ++d) {
      const float mean = stat[d] * cntInv;
      const float var = fmaf(-mean, mean, stat[1024 + d] * cntInv);
      const float a = g[d] * rsqrtf(var + BN_EPS);
      const float c = fmaf(-mean, a, be[d]);
      acc = fmaf(c, W[d * Cout + j], acc);
    }
    bf[j] = acc;
  }
}

// ---------------------------------------------------------------- mlp1 (node-aligned)
__global__ __launch_bounds__(256) void mlp1n_kernel(
    const float* __restrict__ hb, const int* __restrict__ idx,
    const float* __restrict__ w1f, const float* __restrict__ b1f,
    float* __restrict__ xmax, float* __restrict__ xmin,
    float* __restrict__ spart) {
  __shared__ __align__(16) float As[32 * 164];  // [k][row], 160 + 4 pad
  __shared__ __align__(16) float Bs[32][64];
  __shared__ int ids[160];
  __shared__ float red[16][64];
  const int tid = threadIdx.x;
  const int row0 = blockIdx.x * 160;
  const int tn = tid >> 4, tx = tid & 15;
  if (tid < 160) ids[tid] = idx[row0 + tid];
  float acc[10][4] = {};
  for (int kb = 0; kb < 64; kb += 32) {
    __syncthreads();
    for (int f = tid; f < 160 * 8; f += 256) {
      const int r = f >> 3, q = f & 7;
      const int t = blockIdx.x * 16 + r / 10;
      const int jg = ids[r];
      const float4 va = *(const float4*)&hb[(size_t)t * 128 + kb + q * 4];
      const float4 vb = *(const float4*)&hb[(size_t)jg * 128 + 64 + kb + q * 4];
      As[(q * 4 + 0) * 164 + r] = fmaxf(va.x + vb.x, 0.f);
      As[(q * 4 + 1) * 164 + r] = fmaxf(va.y + vb.y, 0.f);
      As[(q * 4 + 2) * 164 + r] = fmaxf(va.z + vb.z, 0.f);
      As[(q * 4 + 3) * 164 + r] = fmaxf(va.w + vb.w, 0.f);
    }
    {
      const int kr = tid >> 4, c4 = tid & 15;
#pragma unroll
      for (int h = 0; h < 2; ++h) {
        const int k2 = kr + h * 16;
        *(float4*)&Bs[k2][c4 * 4] =
            *(const float4*)&w1f[(size_t)(kb + k2) * 64 + c4 * 4];
      }
    }
    __syncthreads();
#pragma unroll
    for (int k = 0; k < 32; ++k) {
      const float* ap = &As[k * 164 + tn * 10];
      const float4 bv = *(const float4*)&Bs[k][tx * 4];
#pragma unroll
      for (int i = 0; i < 10; ++i) {
        const float a = ap[i];
        acc[i][0] = fmaf(a, bv.x, acc[i][0]);
        acc[i][1] = fmaf(a, bv.y, acc[i][1]);
        acc[i][2] = fmaf(a, bv.z, acc[i][2]);
        acc[i][3] = fmaf(a, bv.w, acc[i][3]);
      }
    }
  }
  const int node = blockIdx.x * 16 + tn;
  float s2v[4];
#pragma unroll
  for (int j = 0; j < 4; ++j) {
    const float bj = b1f[tx * 4 + j];
    float mx = -3.4e38f, mn = 3.4e38f, s1 = 0.f, s2 = 0.f;
#pragma unroll
    for (int i = 0; i < 10; ++i) {
      const float v = fmaxf(acc[i][j] + bj, 0.f);
      mx = fmaxf(mx, v); mn = fminf(mn, v);
      s1 += v; s2 = fmaf(v, v, s2);
    }
    xmax[(size_t)node * 64 + tx * 4 + j] = mx;
    xmin[(size_t)node * 64 + tx * 4 + j] = mn;
    red[tn][tx * 4 + j] = s1;
    s2v[j] = s2;
  }
  __syncthreads();
  if (tid < 64) {
    float s = 0.f;
#pragma unroll
    for (int q = 0; q < 16; ++q) s += red[q][tid];
    spart[(size_t)blockIdx.x * 128 + tid] = s;
  }
  __syncthreads();
#pragma unroll
  for (int j = 0; j < 4; ++j) red[tn][tx * 4 + j] = s2v[j];
  __syncthreads();
  if (tid < 64) {
    float s = 0.f;
#pragma unroll
    for (int q = 0; q < 16; ++q) s += red[q][tid];
    spart[(size_t)blockIdx.x * 128 + 64 + tid] = s;
  }
}

// ---------------------------------------------------------------- conv output
__global__ void conv_out_kernel(const float* __restrict__ xmax, const float* __restrict__ xmin,
                                const float* __restrict__ stat, float cntInv,
                                const float* __restrict__ g, const float* __restrict__ be,
                                float* __restrict__ cat, int coff) {
  const int gid = blockIdx.x * blockDim.x + threadIdx.x;
  const int c = gid & 63, t = gid >> 6;
  const float mean = stat[c] * cntInv;
  const float var = fmaf(-mean, mean, stat[1024 + c] * cntInv);
  const float a = g[c] * rsqrtf(var + BN_EPS);
  const float cc = fmaf(-mean, a, be[c]);
  const float v = (a >= 0.f) ? fmaf(a, xmax[gid], cc) : fmaf(a, xmin[gid], cc);
  cat[(size_t)t * 192 + coff + c] = v;
}

// ---------------------------------------------------------------- generic GEMM
// Stats: per-block partials (no atomics) -> spart[blockIdx][128] if spart.
// cmax/cmin: uint atomicMax/Min (exactly associative -> deterministic).
__global__ __launch_bounds__(256) void gemm_kernel(
    const float* __restrict__ A, int lda,
    const float* __restrict__ Bw, int ldb,
    const float* __restrict__ bias, int biasPerGraph,
    float* __restrict__ C,
    float* __restrict__ spart,
    unsigned* __restrict__ cmax, unsigned* __restrict__ cmin,
    int Kdim, int Ncols, int doRelu) {
  __shared__ float As[32][68];
  __shared__ float Bs[32][64];
  const int tid = threadIdx.x;
  const int nbx = Ncols >> 6;
  const int bx = blockIdx.x % nbx, by = blockIdx.x / nbx;
  const int row0 = by << 6, col0 = bx << 6;
  const int tx = tid & 15, ty = tid >> 4;
  float acc[4][4] = {};
  for (int kb = 0; kb < Kdim; kb += 32) {
    __syncthreads();
    {
      const int r = tid >> 3, fc = tid & 7;
#pragma unroll
      for (int h = 0; h < 2; ++h) {
        const int rr = r + h * 32;
        const float4 va = *(const float4*)&A[(size_t)(row0 + rr) * lda + kb + fc * 4];
        As[fc * 4 + 0][rr] = va.x; As[fc * 4 + 1][rr] = va.y;
        As[fc * 4 + 2][rr] = va.z; As[fc * 4 + 3][rr] = va.w;
      }
      const int kr = tid >> 4, c4 = tid & 15;
#pragma unroll
      for (int h = 0; h < 2; ++h) {
        const int k2 = kr + h * 16;
        *(float4*)&Bs[k2][c4 * 4] =
            *(const float4*)&Bw[(size_t)(kb + k2) * ldb + col0 + c4 * 4];
      }
    }
    __syncthreads();
#pragma unroll
    for (int k = 0; k < 32; ++k) {
      const float4 av = *(const float4*)&As[k][ty * 4];
      const float4 bv = *(const float4*)&Bs[k][tx * 4];
      const float a4[4] = {av.x, av.y, av.z, av.w};
      const float b4[4] = {bv.x, bv.y, bv.z, bv.w};
#pragma unroll
      for (int i = 0; i < 4; ++i)
#pragma unroll
        for (int j = 0; j < 4; ++j) acc[i][j] = fmaf(a4[i], b4[j], acc[i][j]);
    }
  }
  const int graph = row0 >> 11;
  const float* bp = bias + (biasPerGraph ? graph * Ncols : 0) + col0 + tx * 4;
  float v[4][4];
#pragma unroll
  for (int j = 0; j < 4; ++j) {
    const float bj = bp[j];
#pragma unroll
    for (int i = 0; i < 4; ++i) {
      const float s = acc[i][j] + bj;
      v[i][j] = doRelu ? fmaxf(s, 0.f) : s;
    }
  }
  if (C) {
#pragma unroll
    for (int i = 0; i < 4; ++i) {
      const float4 st = make_float4(v[i][0], v[i][1], v[i][2], v[i][3]);
      *(float4*)&C[(size_t)(row0 + ty * 4 + i) * Ncols + col0 + tx * 4] = st;
    }
  }
  if (spart) {
    __syncthreads();
#pragma unroll
    for (int j = 0; j < 4; ++j)
      As[ty][tx * 4 + j] = v[0][j] + v[1][j] + v[2][j] + v[3][j];
    __syncthreads();
    if (tid < 64) {
      float s = 0.f;
#pragma unroll
      for (int q = 0; q < 16; ++q) s += As[q][tid];
      spart[(size_t)blockIdx.x * 128 + tid] = s;
    }
    __syncthreads();
#pragma unroll
    for (int j = 0; j < 4; ++j) {
      float s = 0.f;
#pragma unroll
      for (int i = 0; i < 4; ++i) s = fmaf(v[i][j], v[i][j], s);
      As[ty][tx * 4 + j] = s;
    }
    __syncthreads();
    if (tid < 64) {
      float s = 0.f;
#pragma unroll
      for (int q = 0; q < 16; ++q) s += As[q][tid];
      spart[(size_t)blockIdx.x * 128 + 64 + tid] = s;
    }
    if (cmax) {
      __syncthreads();
#pragma unroll
      for (int j = 0; j < 4; ++j)
        As[ty][tx * 4 + j] = fmaxf(fmaxf(v[0][j], v[1][j]), fmaxf(v[2][j], v[3][j]));
      __syncthreads();
      if (tid < 64) {
        float s = As[0][tid];
#pragma unroll
        for (int q = 1; q < 16; ++q) s = fmaxf(s, As[q][tid]);
        atomicMax(&cmax[graph * Ncols + col0 + tid], fkey(s));
      }
      __syncthreads();
#pragma unroll
      for (int j = 0; j < 4; ++j)
        As[ty][tx * 4 + j] = fminf(fminf(v[0][j], v[1][j]), fminf(v[2][j], v[3][j]));
      __syncthreads();
      if (tid < 64) {
        float s = As[0][tid];
#pragma unroll
        for (int q = 1; q < 16; ++q) s = fminf(s, As[q][tid]);
        atomicMin(&cmin[graph * Ncols + col0 + tid], fkey(s));
      }
    }
  }
}

// ---------------------------------------------------------------- pooled (normalized)
__global__ void pool_finalize_kernel(const unsigned* __restrict__ cmax,
                                     const unsigned* __restrict__ cmin,
                                     const float* __restrict__ stat, float cntInv,
                                     const float* __restrict__ g, const float* __restrict__ be,
                                     float* __restrict__ pooled) {
  const int gid = blockIdx.x * blockDim.x + threadIdx.x;
  if (gid >= NBG * 1024) return;
  const int col = gid & 1023;
  const float mean = stat[col] * cntInv;
  const float var = fmaf(-mean, mean, stat[1024 + col] * cntInv);
  const float a = g[col] * rsqrtf(var + BN_EPS);
  const float cc = fmaf(-mean, a, be[col]);
  const float fx = funkey(cmax[gid]), fn = funkey(cmin[gid]);
  pooled[gid] = (a >= 0.f) ? fmaf(a, fx, cc) : fmaf(a, fn, cc);
}

// po[b][j] = m0_b[j] + pooled[b] @ m0_w[192:1216]
__global__ void po_gemm_kernel(const float* __restrict__ pooled,
                               const float* __restrict__ w2,
                               const float* __restrict__ m0b,
                               float* __restrict__ po) {
  const int b = blockIdx.x, j = threadIdx.x;
  const float* pr = pooled + b * 1024;
  float a0 = m0b[j], a1 = 0.f, a2 = 0.f, a3 = 0.f;
  for (int d = 0; d < 1024; d += 4) {
    a0 = fmaf(pr[d + 0], w2[(size_t)(d + 0) * 256 + j], a0);
    a1 = fmaf(pr[d + 1], w2[(size_t)(d + 1) * 256 + j], a1);
    a2 = fmaf(pr[d + 2], w2[(size_t)(d + 2) * 256 + j], a2);
    a3 = fmaf(pr[d + 3], w2[(size_t)(d + 3) * 256 + j], a3);
  }
  po[b * 256 + j] = (a0 + a1) + (a2 + a3);
}

// out[t] = hm1[t] @ m2f + b2f
__global__ __launch_bounds__(256) void m2_gemv_kernel(
    const float* __restrict__ hm1, const float* __restrict__ m2f,
    const float* __restrict__ m2fb, float* __restrict__ out) {
  const int wv = threadIdx.x >> 6, lane = threadIdx.x & 63;
  const int t = blockIdx.x * 4 + wv;
  const float* r = hm1 + (size_t)t * 128;
  float v = fmaf(r[lane], m2f[lane], r[64 + lane] * m2f[64 + lane]);
  for (int off = 32; off; off >>= 1) v += __shfl_down(v, off);
  if (lane == 0) out[t] = v + m2fb[0];
}

// ---------------------------------------------------------------------------
extern "C" void kernel_launch(void* const* d_in, const int* in_sizes, int n_in,
                              void* d_out, int out_size, void* d_ws, size_t ws_size,
                              hipStream_t stream) {
  const float* x = (const float*)d_in[0];
  const float* c_w0[3] = {(const float*)d_in[1], (const float*)d_in[9],  (const float*)d_in[17]};
  const float* c_b0[3] = {(const float*)d_in[2], (const float*)d_in[10], (const float*)d_in[18]};
  const float* c_g0[3] = {(const float*)d_in[3], (const float*)d_in[11], (const float*)d_in[19]};
  const float* c_be0[3]= {(const float*)d_in[4], (const float*)d_in[12], (const float*)d_in[20]};
  const float* c_w1[3] = {(const float*)d_in[5], (const float*)d_in[13], (const float*)d_in[21]};
  const float* c_b1[3] = {(const float*)d_in[6], (const float*)d_in[14], (const float*)d_in[22]};
  const float* c_g1[3] = {(const float*)d_in[7], (const float*)d_in[15], (const float*)d_in[23]};
  const float* c_be1[3]= {(const float*)d_in[8], (const float*)d_in[16], (const float*)d_in[24]};
  const float* l1_w = (const float*)d_in[25];
  const float* l1_b = (const float*)d_in[26];
  const float* l1_g = (const float*)d_in[27];
  const float* l1_be= (const float*)d_in[28];
  const float* m0_w = (const float*)d_in[29];
  const float* m0_b = (const float*)d_in[30];
  const float* m0_g = (const float*)d_in[31];
  const float* m0_be= (const float*)d_in[32];
  const float* m1_w = (const float*)d_in[33];
  const float* m1_b = (const float*)d_in[34];
  const float* m1_g = (const float*)d_in[35];
  const float* m1_be= (const float*)d_in[36];
  const float* m2_w = (const float*)d_in[37];
  const float* m2_b = (const float*)d_in[38];
  float* out = (float*)d_out;

  char* ws = (char*)d_ws;
  float*    stats  = (float*)(ws + 0);
  unsigned* cmax   = (unsigned*)(ws + 73728);
  unsigned* cmin   = (unsigned*)(ws + 106496);
  float*    pooled = (float*)(ws + 139264);
  float*    po     = (float*)(ws + 172032);
  float*    w1f    = (float*)(ws + 180224);
  float*    b1f    = (float*)(ws + 196608);
  float*    m1f    = (float*)(ws + 196864);
  float*    m1fb   = (float*)(ws + 327936);
  float*    m2f    = (float*)(ws + 328448);
  float*    m2fb   = (float*)(ws + 328960);
  int*      idx    = (int*)  (ws + 394752);     // [T][10]
  float*    xmax   = (float*)(ws + 1050112);    // [T][64]
  float*    xmin   = (float*)(ws + 5244416);    // [T][64]
  float*    cat    = (float*)(ws + 9438720);    // [T][192]
  float*    wp[3]  = {(float*)(ws + 22021632),
                      (float*)(ws + 22025216),
                      (float*)(ws + 22058496)};
  float*    bp[3]  = {(float*)(ws + 22024704), (float*)(ws + 22057984),
                      (float*)(ws + 22091264)};
  char*     regA   = ws + 22091776;
  unsigned long long* part = (unsigned long long*)regA;   // [T][2][10]
  float*    hb     = (float*)(regA + 2621440);  // [T][128] (conv phase)
  float*    hm0    = (float*)regA;              // [T][256] (post-conv)
  float*    hm1    = (float*)(regA + 16777216); // [T][128] (post-conv)
  float*    spart  = (float*)(ws + 47257600);   // [<=4096][128] stat partials
  float*    spart2 = (float*)(ws + 49354752);   // [64][128] level-2 partials

  const float cInvE = 1.f / (float)(T * KK);
  const float cInvT = 1.f / (float)T;

  prep_kernel<<<142, 256, 0, stream>>>(stats, cmax, cmin,
                                       c_w0[0], c_b0[0], c_w0[1], c_b0[1], c_w0[2], c_b0[2],
                                       wp[0], bp[0], wp[1], bp[1], wp[2], bp[2]);

  for (int cidx = 0; cidx < 3; ++cidx) {
    const float* Xin; int ldx, Din;
    const int coff = cidx * 64;
    if (cidx == 0) { Xin = x; ldx = 6; Din = 6; }
    else { Xin = cat + (cidx - 1) * 64; ldx = 192; Din = 64; }
    float* st0 = stats + (cidx * 2) * 2048;
    float* st1 = stats + (cidx * 2 + 1) * 2048;

    if (Din == 6)
      knn6_kernel<<<2048, 256, 0, stream>>>(Xin, part);
    else
      knn64_kernel<<<1024, 256, 0, stream>>>(Xin, ldx, part);
    knn_merge2_kernel<<<T / 256, 256, 0, stream>>>(part, idx);
    if (Din == 6)
      nodegemm6_kernel<<<T / 2, 256, 0, stream>>>(Xin, wp[0], bp[0], hb);
    else
      gemm_kernel<<<(T / 64) * 2, 256, 0, stream>>>(
          Xin, ldx, wp[cidx], 128, bp[cidx], 0, hb,
          nullptr, nullptr, nullptr, 64, 128, 0);
    stat0_kernel<<<T * KK / 64, 256, 0, stream>>>(hb, idx, spart);
    statred1_kernel<<<64, 128, 0, stream>>>(spart, T * KK / 64, 40, spart2);
    statredN_kernel<<<1, 128, 0, stream>>>(spart2, 64, 1, st0);
    fold_kernel<<<17, 256, 0, stream>>>(st0, cInvE, c_g0[cidx], c_be0[cidx],
                                        c_w1[cidx], c_b1[cidx], w1f, b1f, 64, 64);
    mlp1n_kernel<<<T * KK / 160, 256, 0, stream>>>(hb, idx, w1f, b1f,
                                                   xmax, xmin, spart);
    statred1_kernel<<<64, 128, 0, stream>>>(spart, T * KK / 160, 16, spart2);
    statredN_kernel<<<1, 128, 0, stream>>>(spart2, 64, 1, st1);
    conv_out_kernel<<<T * 64 / 256, 256, 0, stream>>>(xmax, xmin, st1, cInvE,
                                                      c_g1[cidx], c_be1[cidx], cat, coff);
  }

  float* stl1 = stats + 6 * 2048;
  gemm_kernel<<<(T / 64) * (1024 / 64), 256, 0, stream>>>(
      cat, 192, l1_w, 1024, l1_b, 0, nullptr, spart, cmax, cmin, 192, 1024, 1);
  statredN_kernel<<<16, 128, 0, stream>>>(spart, T / 64, 16, stl1);
  pool_finalize_kernel<<<32, 256, 0, stream>>>(cmax, cmin, stl1, cInvT, l1_g, l1_be, pooled);
  po_gemm_kernel<<<8, 256, 0, stream>>>(pooled, m0_w + 192 * 256, m0_b, po);

  float* stm0 = stats + 7 * 2048;
  gemm_kernel<<<(T / 64) * (256 / 64), 256, 0, stream>>>(
      cat, 192, m0_w, 256, po, 1, hm0, spart, nullptr, nullptr, 192, 256, 1);
  statredN_kernel<<<4, 128, 0, stream>>>(spart, T / 64, 4, stm0);
  fold_kernel<<<129, 256, 0, stream>>>(stm0, cInvT, m0_g, m0_be, m1_w, m1_b, m1f, m1fb, 256, 128);

  float* stm1 = stats + 8 * 2048;
  gemm_kernel<<<(T / 64) * (128 / 64), 256, 0, stream>>>(
      hm0, 256, m1f, 128, m1fb, 0, hm1, spart, nullptr, nullptr, 256, 128, 1);
  statredN_kernel<<<2, 128, 0, stream>>>(spart, T / 64, 2, stm1);
  fold_kernel<<<1, 256, 0, stream>>>(stm1, cInvT, m1_g, m1_be, m2_w, m2_b, m2f, m2fb, 128, 1);
  m2_gemv_kernel<<<T / 4, 256, 0, stream>>>(hm1, m2f, m2fb, out);
}